// Round 1
// baseline (2274.182 us; speedup 1.0000x reference)
//
#include <hip/hip_runtime.h>

typedef __attribute__((ext_vector_type(8))) short short8;
typedef __attribute__((ext_vector_type(4))) float f32x4;

#define NH 32
#define HS 128
#define CDIM 4096

__device__ __forceinline__ ushort f2bf(float f) {
  union { float f; unsigned u; } a; a.f = f;
  unsigned u = a.u;
  return (ushort)((u + 0x7FFFu + ((u >> 16) & 1u)) >> 16);
}
__device__ __forceinline__ float bf2f(ushort h) {
  union { unsigned u; float f; } a; a.u = ((unsigned)h) << 16;
  return a.f;
}

__device__ __forceinline__ void gld16(const void* g, void* l) {
  __builtin_amdgcn_global_load_lds((const __attribute__((address_space(1))) void*)g,
                                   (__attribute__((address_space(3))) void*)l, 16, 0, 0);
}

// ---------------- fp32 -> bf16 cast (vectorized) ----------------
__global__ __launch_bounds__(256) void cast_bf16_kernel(const float* __restrict__ in,
                                                        ushort* __restrict__ out, int n4) {
  int i = blockIdx.x * 256 + threadIdx.x;
  if (i >= n4) return;
  float4 v = ((const float4*)in)[i];
  ushort4 o;
  o.x = f2bf(v.x); o.y = f2bf(v.y); o.z = f2bf(v.z); o.w = f2bf(v.w);
  ((ushort4*)out)[i] = o;
}

// ---------------- GEMM: C[M,N] = A[M,K] @ B[N,K]^T (bf16 in, bf16/f32 out) ----------------
// m97 structure: 128x128 tile, BK=32, 4 waves (2x2), global_load_lds width 16.
template<typename OutT>
__global__ __launch_bounds__(256) void gemm_bt(const ushort* __restrict__ A,
                                               const ushort* __restrict__ B,
                                               OutT* __restrict__ C,
                                               int M, int N, int K) {
  __shared__ ushort As[128 * 32];
  __shared__ ushort Bs[128 * 32];
  const int tid = threadIdx.x;
  const int w = tid >> 6, l = tid & 63, lhi = l >> 4, llo = l & 15;
  const int m0 = blockIdx.x * 128, n0 = blockIdx.y * 128;
  const int wm = (w >> 1) * 64, wn = (w & 1) * 64;

  f32x4 acc[4][4] = {};

  const int c1 = tid, c2 = tid + 256;
  const size_t a1 = (size_t)(m0 + (c1 >> 2)) * K + (c1 & 3) * 8;
  const size_t a2 = (size_t)(m0 + (c2 >> 2)) * K + (c2 & 3) * 8;
  const size_t b1 = (size_t)(n0 + (c1 >> 2)) * K + (c1 & 3) * 8;
  const size_t b2 = (size_t)(n0 + (c2 >> 2)) * K + (c2 & 3) * 8;

  for (int k0 = 0; k0 < K; k0 += 32) {
    gld16(A + a1 + k0, (char*)As + w * 1024);
    gld16(A + a2 + k0, (char*)As + 4096 + w * 1024);
    gld16(B + b1 + k0, (char*)Bs + w * 1024);
    gld16(B + b2 + k0, (char*)Bs + 4096 + w * 1024);
    __syncthreads();
    short8 af[4], bfr[4];
#pragma unroll
    for (int mi = 0; mi < 4; mi++)
      af[mi] = *(const short8*)&As[(wm + mi * 16 + llo) * 32 + lhi * 8];
#pragma unroll
    for (int ni = 0; ni < 4; ni++)
      bfr[ni] = *(const short8*)&Bs[(wn + ni * 16 + llo) * 32 + lhi * 8];
#pragma unroll
    for (int mi = 0; mi < 4; mi++)
#pragma unroll
      for (int ni = 0; ni < 4; ni++)
        acc[mi][ni] = __builtin_amdgcn_mfma_f32_16x16x32_bf16(af[mi], bfr[ni], acc[mi][ni], 0, 0, 0);
    __syncthreads();
  }

#pragma unroll
  for (int mi = 0; mi < 4; mi++) {
#pragma unroll
    for (int ni = 0; ni < 4; ni++) {
      const int col = n0 + wn + ni * 16 + llo;
#pragma unroll
      for (int r = 0; r < 4; r++) {
        size_t idx = (size_t)(m0 + wm + mi * 16 + lhi * 4 + r) * N + col;
        if constexpr (sizeof(OutT) == 4)
          C[idx] = acc[mi][ni][r];
        else
          C[idx] = f2bf(acc[mi][ni][r]);
      }
    }
  }
}

// ---------------- RoPE (in-place on Q and K, bf16) ----------------
__global__ __launch_bounds__(256) void rope_kernel(ushort* __restrict__ Q,
                                                   ushort* __restrict__ Kb,
                                                   const int* __restrict__ pos_ids,
                                                   int nrows) {
  int gid = blockIdx.x * 256 + threadIdx.x;
  int d = gid & 63;
  int row = gid >> 6;  // row = t*NH + h; rows are contiguous 128-elem chunks
  if (row >= nrows) return;
  int t = row >> 5;
  int pos = pos_ids[t];
  float inv = expf((float)d * -0.14391156831212788f);  // -ln(10000)/64
  float ang = (float)pos * inv;
  float s, c;
  sincosf(ang, &s, &c);
  size_t base = (size_t)row * HS;
  {
    float x1 = bf2f(Q[base + d]), x2 = bf2f(Q[base + d + 64]);
    Q[base + d]      = f2bf(x1 * c - x2 * s);
    Q[base + d + 64] = f2bf(x2 * c + x1 * s);
  }
  {
    float x1 = bf2f(Kb[base + d]), x2 = bf2f(Kb[base + d + 64]);
    Kb[base + d]      = f2bf(x1 * c - x2 * s);
    Kb[base + d + 64] = f2bf(x2 * c + x1 * s);
  }
}

// ---------------- Causal flash attention ----------------
// grid (T/64, NH); 4 waves/block; wave w owns q rows [qb*64+w*16, +16); KV tile = 32.
__global__ __launch_bounds__(256) void flash_attn(const ushort* __restrict__ Q,
                                                  const ushort* __restrict__ K,
                                                  const ushort* __restrict__ V,
                                                  ushort* __restrict__ O) {
  __shared__ ushort Vt[128 * 40];    // V transposed: Vt[d][kv], pad 40 keeps 16B row align
  __shared__ ushort Pl[4][16 * 32];  // per-wave P tile
  const int tid = threadIdx.x;
  const int w = tid >> 6, l = tid & 63, lhi = l >> 4, llo = l & 15;
  const int qb = blockIdx.x, h = blockIdx.y;
  const int qr0 = qb * 64 + w * 16;

  short8 aq[4];
  {
    const ushort* qp = Q + (size_t)(qr0 + llo) * CDIM + h * HS + lhi * 8;
#pragma unroll
    for (int ki = 0; ki < 4; ki++) aq[ki] = *(const short8*)(qp + ki * 32);
  }
  f32x4 acc[8] = {};
  float m[4] = {-1e30f, -1e30f, -1e30f, -1e30f};
  float lsum[4] = {0.f, 0.f, 0.f, 0.f};

  const int kv_end = qb * 64 + 64;
  const int qrow_b = qr0 + lhi * 4;

  for (int kv0 = 0; kv0 < kv_end; kv0 += 32) {
    __syncthreads();  // prior PV reads of Vt done before restage
    // stage V^T cooperatively: 512 chunks of 8 elems
#pragma unroll
    for (int it = 0; it < 2; it++) {
      int c = tid + it * 256;
      int row = c >> 4, col8 = (c & 15) * 8;
      short8 v8 = *(const short8*)(V + (size_t)(kv0 + row) * CDIM + h * HS + col8);
#pragma unroll
      for (int j = 0; j < 8; j++) Vt[(col8 + j) * 40 + row] = (ushort)v8[j];
    }
    // S = Q K^T (K frags straight from global; L2-resident per head)
    f32x4 s[2];
#pragma unroll
    for (int nt = 0; nt < 2; nt++) {
      f32x4 sa = {0.f, 0.f, 0.f, 0.f};
      const ushort* kp = K + (size_t)(kv0 + nt * 16 + llo) * CDIM + h * HS + lhi * 8;
#pragma unroll
      for (int ki = 0; ki < 4; ki++) {
        short8 kf = *(const short8*)(kp + ki * 32);
        sa = __builtin_amdgcn_mfma_f32_16x16x32_bf16(aq[ki], kf, sa, 0, 0, 0);
      }
      s[nt] = sa;
    }
    const bool need_mask = (kv0 + 31) > qr0;
#pragma unroll
    for (int nt = 0; nt < 2; nt++) {
      int kv = kv0 + nt * 16 + llo;
#pragma unroll
      for (int j = 0; j < 4; j++) {
        float sv = s[nt][j] * 0.08838834764831845f;  // 1/sqrt(128)
        if (need_mask && kv > qrow_b + j) sv = -1e30f;
        s[nt][j] = sv;
      }
    }
    // online softmax (rows live on 16-lane groups)
    float sc[4];
#pragma unroll
    for (int r = 0; r < 4; r++) {
      float lm = fmaxf(s[0][r], s[1][r]);
      lm = fmaxf(lm, __shfl_xor(lm, 1));
      lm = fmaxf(lm, __shfl_xor(lm, 2));
      lm = fmaxf(lm, __shfl_xor(lm, 4));
      lm = fmaxf(lm, __shfl_xor(lm, 8));
      float mn = fmaxf(m[r], lm);
      sc[r] = __expf(m[r] - mn);
      m[r] = mn;
      float p0 = __expf(s[0][r] - mn);
      float p1 = __expf(s[1][r] - mn);
      s[0][r] = p0; s[1][r] = p1;
      float rsum = p0 + p1;
      rsum += __shfl_xor(rsum, 1);
      rsum += __shfl_xor(rsum, 2);
      rsum += __shfl_xor(rsum, 4);
      rsum += __shfl_xor(rsum, 8);
      lsum[r] = lsum[r] * sc[r] + rsum;
    }
#pragma unroll
    for (int on = 0; on < 8; on++)
#pragma unroll
      for (int r = 0; r < 4; r++) acc[on][r] *= sc[r];
    // P -> LDS (per-wave, D-layout scatter), then read back as A-fragment
    ushort* pw = Pl[w];
#pragma unroll
    for (int nt = 0; nt < 2; nt++)
#pragma unroll
      for (int r = 0; r < 4; r++)
        pw[(lhi * 4 + r) * 32 + nt * 16 + llo] = f2bf(s[nt][r]);
    __syncthreads();  // Vt staged; (Pl is wave-private, lgkmcnt handles RAW)
    short8 pf = *(const short8*)(pw + llo * 32 + lhi * 8);
#pragma unroll
    for (int on = 0; on < 8; on++) {
      short8 vf = *(const short8*)(&Vt[(on * 16 + llo) * 40 + lhi * 8]);
      acc[on] = __builtin_amdgcn_mfma_f32_16x16x32_bf16(pf, vf, acc[on], 0, 0, 0);
    }
  }
#pragma unroll
  for (int r = 0; r < 4; r++) m[r] = 1.0f / lsum[r];  // reuse as 1/l
#pragma unroll
  for (int on = 0; on < 8; on++)
#pragma unroll
    for (int r = 0; r < 4; r++)
      O[(size_t)(qrow_b + r) * CDIM + h * HS + on * 16 + llo] = f2bf(acc[on][r] * m[r]);
}

// ---------------- launch ----------------
extern "C" void kernel_launch(void* const* d_in, const int* in_sizes, int n_in,
                              void* d_out, int out_size, void* d_ws, size_t ws_size,
                              hipStream_t stream) {
  const float* hs = (const float*)d_in[0];
  const int* pos = (const int*)d_in[1];
  const float* Wq = (const float*)d_in[2];
  const float* Wk = (const float*)d_in[3];
  const float* Wv = (const float*)d_in[4];
  const float* Wo = (const float*)d_in[5];
  float* out = (float*)d_out;

  const int T = 4096;
  const size_t elems = (size_t)T * CDIM;

  ushort* hsb  = (ushort*)d_ws;      // also reused as attention output
  ushort* wbuf = hsb + elems;        // current weight (bf16), reused 4x
  ushort* qb   = wbuf + elems;
  ushort* kb   = qb + elems;
  ushort* vb   = kb + elems;
  ushort* attn = hsb;

  const int n4 = (int)(elems / 4);
  const int castBlocks = (n4 + 255) / 256;
  dim3 ggrid(32, 32);

  cast_bf16_kernel<<<castBlocks, 256, 0, stream>>>(hs, hsb, n4);

  cast_bf16_kernel<<<castBlocks, 256, 0, stream>>>(Wq, wbuf, n4);
  gemm_bt<ushort><<<ggrid, 256, 0, stream>>>(hsb, wbuf, qb, 4096, 4096, 4096);

  cast_bf16_kernel<<<castBlocks, 256, 0, stream>>>(Wk, wbuf, n4);
  gemm_bt<ushort><<<ggrid, 256, 0, stream>>>(hsb, wbuf, kb, 4096, 4096, 4096);

  cast_bf16_kernel<<<castBlocks, 256, 0, stream>>>(Wv, wbuf, n4);
  gemm_bt<ushort><<<ggrid, 256, 0, stream>>>(hsb, wbuf, vb, 4096, 4096, 4096);

  rope_kernel<<<(T * NH * 64) / 256, 256, 0, stream>>>(qb, kb, pos, T * NH);

  flash_attn<<<dim3(T / 64, NH), 256, 0, stream>>>(qb, kb, vb, attn);

  cast_bf16_kernel<<<castBlocks, 256, 0, stream>>>(Wo, wbuf, n4);
  gemm_bt<float><<<ggrid, 256, 0, stream>>>(attn, wbuf, out, 4096, 4096, 4096);
}

// Round 2
// 1817.939 us; speedup vs baseline: 1.2510x; 1.2510x over previous
//
#include <hip/hip_runtime.h>

typedef __attribute__((ext_vector_type(8))) short short8;
typedef __attribute__((ext_vector_type(4))) short short4v;
typedef __attribute__((ext_vector_type(4))) float f32x4;

#define NH 32
#define HS 128
#define CDIM 4096
#define QBLK 128
#define KVBLK 64

__device__ __forceinline__ ushort f2bf(float f) {
  union { float f; unsigned u; } a; a.f = f;
  unsigned u = a.u;
  return (ushort)((u + 0x7FFFu + ((u >> 16) & 1u)) >> 16);
}
__device__ __forceinline__ float bf2f(ushort h) {
  union { unsigned u; float f; } a; a.u = ((unsigned)h) << 16;
  return a.f;
}

__device__ __forceinline__ void gld16(const void* g, void* l) {
  __builtin_amdgcn_global_load_lds((const __attribute__((address_space(1))) void*)g,
                                   (__attribute__((address_space(3))) void*)l, 16, 0, 0);
}

__device__ __forceinline__ unsigned lds_off(const void* p) {
  return (unsigned)(uintptr_t)(const __attribute__((address_space(3))) void*)p;
}

template<int OFF>
__device__ __forceinline__ short4v ds_tr16(unsigned addr) {
  short4v r;
  asm volatile("ds_read_b64_tr_b16 %0, %1 offset:%c2" : "=v"(r) : "v"(addr), "i"(OFF));
  return r;
}

// ---------------- fp32 -> bf16 cast (vectorized) ----------------
__global__ __launch_bounds__(256) void cast_bf16_kernel(const float* __restrict__ in,
                                                        ushort* __restrict__ out, int n4) {
  int i = blockIdx.x * 256 + threadIdx.x;
  if (i >= n4) return;
  float4 v = ((const float4*)in)[i];
  ushort4 o;
  o.x = f2bf(v.x); o.y = f2bf(v.y); o.z = f2bf(v.z); o.w = f2bf(v.w);
  ((ushort4*)out)[i] = o;
}

// ---------------- GEMM: C[M,N] = A[M,K] @ B[N,K]^T ----------------
template<typename OutT>
__global__ __launch_bounds__(256) void gemm_bt(const ushort* __restrict__ A,
                                               const ushort* __restrict__ B,
                                               OutT* __restrict__ C,
                                               int M, int N, int K) {
  __shared__ ushort As[128 * 32];
  __shared__ ushort Bs[128 * 32];
  const int tid = threadIdx.x;
  const int w = tid >> 6, l = tid & 63, lhi = l >> 4, llo = l & 15;
  const int m0 = blockIdx.x * 128, n0 = blockIdx.y * 128;
  const int wm = (w >> 1) * 64, wn = (w & 1) * 64;

  f32x4 acc[4][4] = {};

  const int c1 = tid, c2 = tid + 256;
  const size_t a1 = (size_t)(m0 + (c1 >> 2)) * K + (c1 & 3) * 8;
  const size_t a2 = (size_t)(m0 + (c2 >> 2)) * K + (c2 & 3) * 8;
  const size_t b1 = (size_t)(n0 + (c1 >> 2)) * K + (c1 & 3) * 8;
  const size_t b2 = (size_t)(n0 + (c2 >> 2)) * K + (c2 & 3) * 8;

  for (int k0 = 0; k0 < K; k0 += 32) {
    gld16(A + a1 + k0, (char*)As + w * 1024);
    gld16(A + a2 + k0, (char*)As + 4096 + w * 1024);
    gld16(B + b1 + k0, (char*)Bs + w * 1024);
    gld16(B + b2 + k0, (char*)Bs + 4096 + w * 1024);
    __syncthreads();
    short8 af[4], bfr[4];
#pragma unroll
    for (int mi = 0; mi < 4; mi++)
      af[mi] = *(const short8*)&As[(wm + mi * 16 + llo) * 32 + lhi * 8];
#pragma unroll
    for (int ni = 0; ni < 4; ni++)
      bfr[ni] = *(const short8*)&Bs[(wn + ni * 16 + llo) * 32 + lhi * 8];
#pragma unroll
    for (int mi = 0; mi < 4; mi++)
#pragma unroll
      for (int ni = 0; ni < 4; ni++)
        acc[mi][ni] = __builtin_amdgcn_mfma_f32_16x16x32_bf16(af[mi], bfr[ni], acc[mi][ni], 0, 0, 0);
    __syncthreads();
  }

#pragma unroll
  for (int mi = 0; mi < 4; mi++) {
#pragma unroll
    for (int ni = 0; ni < 4; ni++) {
      const int col = n0 + wn + ni * 16 + llo;
#pragma unroll
      for (int r = 0; r < 4; r++) {
        size_t idx = (size_t)(m0 + wm + mi * 16 + lhi * 4 + r) * N + col;
        if constexpr (sizeof(OutT) == 4)
          C[idx] = acc[mi][ni][r];
        else
          C[idx] = f2bf(acc[mi][ni][r]);
      }
    }
  }
}

// ---------------- RoPE (in-place on Q and K, bf16) ----------------
__global__ __launch_bounds__(256) void rope_kernel(ushort* __restrict__ Q,
                                                   ushort* __restrict__ Kb,
                                                   const int* __restrict__ pos_ids,
                                                   int nrows) {
  int gid = blockIdx.x * 256 + threadIdx.x;
  int d = gid & 63;
  int row = gid >> 6;
  if (row >= nrows) return;
  int t = row >> 5;
  int pos = pos_ids[t];
  float inv = expf((float)d * -0.14391156831212788f);  // -ln(10000)/64
  float ang = (float)pos * inv;
  float s, c;
  sincosf(ang, &s, &c);
  size_t base = (size_t)row * HS;
  {
    float x1 = bf2f(Q[base + d]), x2 = bf2f(Q[base + d + 64]);
    Q[base + d]      = f2bf(x1 * c - x2 * s);
    Q[base + d + 64] = f2bf(x2 * c + x1 * s);
  }
  {
    float x1 = bf2f(Kb[base + d]), x2 = bf2f(Kb[base + d + 64]);
    Kb[base + d]      = f2bf(x1 * c - x2 * s);
    Kb[base + d + 64] = f2bf(x2 * c + x1 * s);
  }
}

// ---------------- Causal flash attention (v2) ----------------
// grid (T/128, NH); 4 waves; wave w owns q rows [qb*128+w*32, +32); KV tile = 64.
// K in LDS: [64][128] bf16, 16B-chunk XOR swizzle  cl = cg ^ (row&7).
// V in LDS: [64][128] bf16, 16B-chunk XOR swizzle  cl = cg ^ ((row&3)|(((row>>3)&1)<<2)),
//           consumed via ds_read_b64_tr_b16.
__global__ __launch_bounds__(256) void flash_attn(const ushort* __restrict__ Q,
                                                  const ushort* __restrict__ K,
                                                  const ushort* __restrict__ V,
                                                  ushort* __restrict__ O) {
  __shared__ ushort Ks[KVBLK * HS];
  __shared__ ushort Vs[KVBLK * HS];
  __shared__ ushort Ps[4][32 * 72];   // per-wave P tile, stride 72 (pad +8)
  const int tid = threadIdx.x;
  const int w = tid >> 6, l = tid & 63, lhi = l >> 4, llo = l & 15;
  const int qb = blockIdx.x, h = blockIdx.y;
  const int qr0 = qb * QBLK + w * 32;

  // Q fragments (A-operand), 2 m-frags x 4 k-steps
  short8 aq[2][4];
#pragma unroll
  for (int mf = 0; mf < 2; mf++) {
    const ushort* qp = Q + (size_t)(qr0 + mf * 16 + llo) * CDIM + h * HS + lhi * 8;
#pragma unroll
    for (int ki = 0; ki < 4; ki++) aq[mf][ki] = *(const short8*)(qp + ki * 32);
  }

  f32x4 acc[2][8] = {};
  f32x4 mrow[2], lrow[2];
#pragma unroll
  for (int mf = 0; mf < 2; mf++) {
#pragma unroll
    for (int j = 0; j < 4; j++) { mrow[mf][j] = -1e30f; lrow[mf][j] = 0.f; }
  }

  // tr-read per-lane constants
  const int g = llo >> 2, c = llo & 3;
  const int swz = g | ((lhi & 1) << 2);
  const int c1 = c >> 1;
  const int swL = swz & 1, swH = swz & 6;
  const unsigned trbase = lds_off(Vs) + (unsigned)((lhi * 8 + g) * 256 + ((c1 ^ swL) << 4) + (c & 1) * 8);

  ushort* pw = Ps[w];
  const int kv_end = qb * QBLK + QBLK;
  const float scale = 0.08838834764831845f;  // 1/sqrt(128)

  for (int kv0 = 0; kv0 < kv_end; kv0 += KVBLK) {
    __syncthreads();  // prior tile's LDS reads complete
    // stage K and V: 4 rounds x (256 lanes x 16B) each
#pragma unroll
    for (int r = 0; r < 4; r++) {
      int slot = r * 256 + tid;
      int row = slot >> 4, ch = slot & 15;
      int chK = ch ^ (row & 7);
      int chV = ch ^ ((row & 3) | (((row >> 3) & 1) << 2));
      const ushort* kg = K + (size_t)(kv0 + row) * CDIM + h * HS + chK * 8;
      const ushort* vg = V + (size_t)(kv0 + row) * CDIM + h * HS + chV * 8;
      gld16(kg, (char*)Ks + (r * 256 + w * 64) * 16);
      gld16(vg, (char*)Vs + (r * 256 + w * 64) * 16);
    }
    const bool active = (kv0 <= qr0 + 31);
    __syncthreads();  // staged data visible
    if (!active) continue;

    // ---- S = Q K^T ----
    f32x4 s[2][4];
#pragma unroll
    for (int nt = 0; nt < 4; nt++) {
      const int krow = nt * 16 + llo;
      const char* kr = (const char*)Ks + krow * 256;
      short8 kf[4];
#pragma unroll
      for (int ki = 0; ki < 4; ki++)
        kf[ki] = *(const short8*)(kr + (((ki * 4 + lhi) ^ (krow & 7)) << 4));
      f32x4 s0 = {0.f, 0.f, 0.f, 0.f}, s1 = {0.f, 0.f, 0.f, 0.f};
#pragma unroll
      for (int ki = 0; ki < 4; ki++) {
        s0 = __builtin_amdgcn_mfma_f32_16x16x32_bf16(aq[0][ki], kf[ki], s0, 0, 0, 0);
        s1 = __builtin_amdgcn_mfma_f32_16x16x32_bf16(aq[1][ki], kf[ki], s1, 0, 0, 0);
      }
      s[0][nt] = s0; s[1][nt] = s1;
    }

    // ---- scale + causal mask ----
    const bool needm = (kv0 + KVBLK - 1 > qr0);
#pragma unroll
    for (int mf = 0; mf < 2; mf++) {
#pragma unroll
      for (int nt = 0; nt < 4; nt++) {
        int kvi = kv0 + nt * 16 + llo;
#pragma unroll
        for (int j = 0; j < 4; j++) {
          float sv = s[mf][nt][j] * scale;
          if (needm && kvi > qr0 + mf * 16 + lhi * 4 + j) sv = -1e30f;
          s[mf][nt][j] = sv;
        }
      }
    }

    // ---- online softmax (row r lives on the 16 llo-lanes of group lhi) ----
#pragma unroll
    for (int mf = 0; mf < 2; mf++) {
      float sc[4];
#pragma unroll
      for (int j = 0; j < 4; j++) {
        float rm = fmaxf(fmaxf(s[mf][0][j], s[mf][1][j]), fmaxf(s[mf][2][j], s[mf][3][j]));
        rm = fmaxf(rm, __shfl_xor(rm, 1));
        rm = fmaxf(rm, __shfl_xor(rm, 2));
        rm = fmaxf(rm, __shfl_xor(rm, 4));
        rm = fmaxf(rm, __shfl_xor(rm, 8));
        float mn = fmaxf(mrow[mf][j], rm);
        sc[j] = __expf(mrow[mf][j] - mn);
        mrow[mf][j] = mn;
        float rs = 0.f;
#pragma unroll
        for (int nt = 0; nt < 4; nt++) {
          float p = __expf(s[mf][nt][j] - mn);
          s[mf][nt][j] = p;
          rs += p;
        }
        rs += __shfl_xor(rs, 1);
        rs += __shfl_xor(rs, 2);
        rs += __shfl_xor(rs, 4);
        rs += __shfl_xor(rs, 8);
        lrow[mf][j] = lrow[mf][j] * sc[j] + rs;
      }
#pragma unroll
      for (int on = 0; on < 8; on++)
#pragma unroll
        for (int j = 0; j < 4; j++) acc[mf][on][j] *= sc[j];
      // P -> per-wave LDS (D-layout scatter)
#pragma unroll
      for (int nt = 0; nt < 4; nt++)
#pragma unroll
        for (int j = 0; j < 4; j++)
          pw[(mf * 16 + lhi * 4 + j) * 72 + nt * 16 + llo] = f2bf(s[mf][nt][j]);
    }

    // ---- O += P V ----
#pragma unroll
    for (int ks = 0; ks < 2; ks++) {
      short8 pf0 = *(const short8*)(pw + (llo) * 72 + ks * 32 + lhi * 8);
      short8 pf1 = *(const short8*)(pw + (16 + llo) * 72 + ks * 32 + lhi * 8);
      short4v vl[8], vh[8];
      if (ks == 0) {
#pragma unroll
        for (int on = 0; on < 8; on++) {
          unsigned a = trbase + (unsigned)(((on * 2) ^ swH) << 4);
          vl[on] = ds_tr16<0>(a);
          vh[on] = ds_tr16<1024>(a);
        }
      } else {
#pragma unroll
        for (int on = 0; on < 8; on++) {
          unsigned a = trbase + (unsigned)(((on * 2) ^ swH) << 4);
          vl[on] = ds_tr16<8192>(a);
          vh[on] = ds_tr16<9216>(a);
        }
      }
      asm volatile("s_waitcnt lgkmcnt(0)" ::: "memory");
      __builtin_amdgcn_sched_barrier(0);
#pragma unroll
      for (int on = 0; on < 8; on++) {
        short8 vf = __builtin_shufflevector(vl[on], vh[on], 0, 1, 2, 3, 4, 5, 6, 7);
        acc[0][on] = __builtin_amdgcn_mfma_f32_16x16x32_bf16(pf0, vf, acc[0][on], 0, 0, 0);
        acc[1][on] = __builtin_amdgcn_mfma_f32_16x16x32_bf16(pf1, vf, acc[1][on], 0, 0, 0);
      }
    }
  }

  // ---- epilogue ----
  float rinv[2][4];
#pragma unroll
  for (int mf = 0; mf < 2; mf++)
#pragma unroll
    for (int j = 0; j < 4; j++) rinv[mf][j] = 1.0f / lrow[mf][j];
#pragma unroll
  for (int mf = 0; mf < 2; mf++)
#pragma unroll
    for (int on = 0; on < 8; on++)
#pragma unroll
      for (int j = 0; j < 4; j++)
        O[(size_t)(qr0 + mf * 16 + lhi * 4 + j) * CDIM + h * HS + on * 16 + llo] =
            f2bf(acc[mf][on][j] * rinv[mf][j]);
}

// ---------------- launch ----------------
extern "C" void kernel_launch(void* const* d_in, const int* in_sizes, int n_in,
                              void* d_out, int out_size, void* d_ws, size_t ws_size,
                              hipStream_t stream) {
  const float* hs = (const float*)d_in[0];
  const int* pos = (const int*)d_in[1];
  const float* Wq = (const float*)d_in[2];
  const float* Wk = (const float*)d_in[3];
  const float* Wv = (const float*)d_in[4];
  const float* Wo = (const float*)d_in[5];
  float* out = (float*)d_out;

  const int T = 4096;
  const size_t elems = (size_t)T * CDIM;

  ushort* hsb  = (ushort*)d_ws;      // also reused as attention output
  ushort* wbuf = hsb + elems;        // current weight (bf16), reused 4x
  ushort* qb   = wbuf + elems;
  ushort* kb   = qb + elems;
  ushort* vb   = kb + elems;
  ushort* attn = hsb;

  const int n4 = (int)(elems / 4);
  const int castBlocks = (n4 + 255) / 256;
  dim3 ggrid(32, 32);

  cast_bf16_kernel<<<castBlocks, 256, 0, stream>>>(hs, hsb, n4);

  cast_bf16_kernel<<<castBlocks, 256, 0, stream>>>(Wq, wbuf, n4);
  gemm_bt<ushort><<<ggrid, 256, 0, stream>>>(hsb, wbuf, qb, 4096, 4096, 4096);

  cast_bf16_kernel<<<castBlocks, 256, 0, stream>>>(Wk, wbuf, n4);
  gemm_bt<ushort><<<ggrid, 256, 0, stream>>>(hsb, wbuf, kb, 4096, 4096, 4096);

  cast_bf16_kernel<<<castBlocks, 256, 0, stream>>>(Wv, wbuf, n4);
  gemm_bt<ushort><<<ggrid, 256, 0, stream>>>(hsb, wbuf, vb, 4096, 4096, 4096);

  rope_kernel<<<(T * NH * 64) / 256, 256, 0, stream>>>(qb, kb, pos, T * NH);

  flash_attn<<<dim3(T / QBLK, NH), 256, 0, stream>>>(qb, kb, vb, attn);

  cast_bf16_kernel<<<castBlocks, 256, 0, stream>>>(Wo, wbuf, n4);
  gemm_bt<float><<<ggrid, 256, 0, stream>>>(attn, wbuf, out, 4096, 4096, 4096);
}

// Round 3
// 1414.501 us; speedup vs baseline: 1.6078x; 1.2852x over previous
//
#include <hip/hip_runtime.h>

typedef __attribute__((ext_vector_type(8))) short short8;
typedef __attribute__((ext_vector_type(4))) short short4v;
typedef __attribute__((ext_vector_type(4))) float f32x4;

#define NH 32
#define HS 128
#define CDIM 4096
#define QBLK 128
#define KVBLK 64
#define NQT 32  // T / QBLK

__device__ __forceinline__ ushort f2bf(float f) {
  union { float f; unsigned u; } a; a.f = f;
  unsigned u = a.u;
  return (ushort)((u + 0x7FFFu + ((u >> 16) & 1u)) >> 16);
}
__device__ __forceinline__ float bf2f(ushort h) {
  union { unsigned u; float f; } a; a.u = ((unsigned)h) << 16;
  return a.f;
}

__device__ __forceinline__ void gld16(const void* g, void* l) {
  __builtin_amdgcn_global_load_lds((const __attribute__((address_space(1))) void*)g,
                                   (__attribute__((address_space(3))) void*)l, 16, 0, 0);
}

__device__ __forceinline__ unsigned lds_off(const void* p) {
  return (unsigned)(uintptr_t)(const __attribute__((address_space(3))) void*)p;
}

template<int OFF>
__device__ __forceinline__ short4v ds_tr16(unsigned addr) {
  short4v r;
  asm volatile("ds_read_b64_tr_b16 %0, %1 offset:%c2" : "=v"(r) : "v"(addr), "i"(OFF));
  return r;
}

// ---------------- fp32 -> bf16 cast (vectorized) ----------------
__global__ __launch_bounds__(256) void cast_bf16_kernel(const float* __restrict__ in,
                                                        ushort* __restrict__ out, int n4) {
  int i = blockIdx.x * 256 + threadIdx.x;
  if (i >= n4) return;
  float4 v = ((const float4*)in)[i];
  ushort4 o;
  o.x = f2bf(v.x); o.y = f2bf(v.y); o.z = f2bf(v.z); o.w = f2bf(v.w);
  ((ushort4*)out)[i] = o;
}

// ---------------- GEMM: C[M,N] = A[M,K] @ B[N,K]^T ----------------
template<typename OutT>
__global__ __launch_bounds__(256) void gemm_bt(const ushort* __restrict__ A,
                                               const ushort* __restrict__ B,
                                               OutT* __restrict__ C,
                                               int M, int N, int K) {
  __shared__ ushort As[128 * 32];
  __shared__ ushort Bs[128 * 32];
  const int tid = threadIdx.x;
  const int w = tid >> 6, l = tid & 63, lhi = l >> 4, llo = l & 15;
  const int m0 = blockIdx.x * 128, n0 = blockIdx.y * 128;
  const int wm = (w >> 1) * 64, wn = (w & 1) * 64;

  f32x4 acc[4][4] = {};

  const int c1 = tid, c2 = tid + 256;
  const size_t a1 = (size_t)(m0 + (c1 >> 2)) * K + (c1 & 3) * 8;
  const size_t a2 = (size_t)(m0 + (c2 >> 2)) * K + (c2 & 3) * 8;
  const size_t b1 = (size_t)(n0 + (c1 >> 2)) * K + (c1 & 3) * 8;
  const size_t b2 = (size_t)(n0 + (c2 >> 2)) * K + (c2 & 3) * 8;

  for (int k0 = 0; k0 < K; k0 += 32) {
    gld16(A + a1 + k0, (char*)As + w * 1024);
    gld16(A + a2 + k0, (char*)As + 4096 + w * 1024);
    gld16(B + b1 + k0, (char*)Bs + w * 1024);
    gld16(B + b2 + k0, (char*)Bs + 4096 + w * 1024);
    __syncthreads();
    short8 af[4], bfr[4];
#pragma unroll
    for (int mi = 0; mi < 4; mi++)
      af[mi] = *(const short8*)&As[(wm + mi * 16 + llo) * 32 + lhi * 8];
#pragma unroll
    for (int ni = 0; ni < 4; ni++)
      bfr[ni] = *(const short8*)&Bs[(wn + ni * 16 + llo) * 32 + lhi * 8];
#pragma unroll
    for (int mi = 0; mi < 4; mi++)
#pragma unroll
      for (int ni = 0; ni < 4; ni++)
        acc[mi][ni] = __builtin_amdgcn_mfma_f32_16x16x32_bf16(af[mi], bfr[ni], acc[mi][ni], 0, 0, 0);
    __syncthreads();
  }

#pragma unroll
  for (int mi = 0; mi < 4; mi++) {
#pragma unroll
    for (int ni = 0; ni < 4; ni++) {
      const int col = n0 + wn + ni * 16 + llo;
#pragma unroll
      for (int r = 0; r < 4; r++) {
        size_t idx = (size_t)(m0 + wm + mi * 16 + lhi * 4 + r) * N + col;
        if constexpr (sizeof(OutT) == 4)
          C[idx] = acc[mi][ni][r];
        else
          C[idx] = f2bf(acc[mi][ni][r]);
      }
    }
  }
}

// ---------------- RoPE (in-place on Q and K, bf16) ----------------
__global__ __launch_bounds__(256) void rope_kernel(ushort* __restrict__ Q,
                                                   ushort* __restrict__ Kb,
                                                   const int* __restrict__ pos_ids,
                                                   int nrows) {
  int gid = blockIdx.x * 256 + threadIdx.x;
  int d = gid & 63;
  int row = gid >> 6;
  if (row >= nrows) return;
  int t = row >> 5;
  int pos = pos_ids[t];
  float inv = expf((float)d * -0.14391156831212788f);  // -ln(10000)/64
  float ang = (float)pos * inv;
  float s, c;
  sincosf(ang, &s, &c);
  size_t base = (size_t)row * HS;
  {
    float x1 = bf2f(Q[base + d]), x2 = bf2f(Q[base + d + 64]);
    Q[base + d]      = f2bf(x1 * c - x2 * s);
    Q[base + d + 64] = f2bf(x2 * c + x1 * s);
  }
  {
    float x1 = bf2f(Kb[base + d]), x2 = bf2f(Kb[base + d + 64]);
    Kb[base + d]      = f2bf(x1 * c - x2 * s);
    Kb[base + d + 64] = f2bf(x2 * c + x1 * s);
  }
}

// ---------------- Causal flash attention (v3) ----------------
// grid (NQT/2, NH); block (qb,h) processes q-tiles {qb, NQT-1-qb} sequentially
// -> uniform 66 KV-tile-iters per block. 4 waves; wave w owns q rows [qt*128+w*32,+32).
// K LDS: [64][128] bf16, 16B-chunk XOR swizzle  cl = cg ^ (row&7).
// V LDS: [64][128] bf16, 16B-chunk XOR swizzle  cl = cg ^ ((row&3)|(((row>>3)&1)<<2)),
//        consumed via ds_read_b64_tr_b16.
// Staging: T14 reg-prefetch (issue loads for tile t+1 before computing tile t).
__global__ __launch_bounds__(256) void flash_attn(const ushort* __restrict__ Q,
                                                  const ushort* __restrict__ K,
                                                  const ushort* __restrict__ V,
                                                  ushort* __restrict__ O) {
  __shared__ ushort Ks[KVBLK * HS];
  __shared__ ushort Vs[KVBLK * HS];
  __shared__ ushort Ps[4][32 * 72];   // per-wave P tile, stride 72 (pad +8)
  const int tid = threadIdx.x;
  const int w = tid >> 6, l = tid & 63, lhi = l >> 4, llo = l & 15;
  const int qbp = blockIdx.x, h = blockIdx.y;

  // tr-read per-lane constants (V path)
  const int g = llo >> 2, c = llo & 3;
  const int swz = g | ((lhi & 1) << 2);
  const int c1 = c >> 1;
  const int swL = swz & 1, swH = swz & 6;
  const unsigned trbase = lds_off(Vs) + (unsigned)((lhi * 8 + g) * 256 + ((c1 ^ swL) << 4) + (c & 1) * 8);

  // staging per-lane constants
  const int srow = tid >> 4, sch = tid & 15;   // +16 rows per round
  const int schK0 = sch ^ (srow & 7);
  const int schV0 = sch ^ ((srow & 3) | (((srow >> 3) & 1) << 2));

  ushort* pw = Ps[w];
  const float scale = 0.08838834764831845f;  // 1/sqrt(128)

  short8 kreg[4], vreg[4];

  for (int ph = 0; ph < 2; ph++) {
    const int qt = ph ? (NQT - 1 - qbp) : qbp;
    const int qr0 = qt * QBLK + w * 32;
    const int ntile = 2 * qt + 2;

    // Q fragments (A-operand), 2 m-frags x 4 k-steps
    short8 aq[2][4];
#pragma unroll
    for (int mf = 0; mf < 2; mf++) {
      const ushort* qp = Q + (size_t)(qr0 + mf * 16 + llo) * CDIM + h * HS + lhi * 8;
#pragma unroll
      for (int ki = 0; ki < 4; ki++) aq[mf][ki] = *(const short8*)(qp + ki * 32);
    }

    f32x4 acc[2][8] = {};
    f32x4 mrow[2], lrow[2];
#pragma unroll
    for (int mf = 0; mf < 2; mf++) {
#pragma unroll
      for (int j = 0; j < 4; j++) { mrow[mf][j] = -1e30f; lrow[mf][j] = 0.f; }
    }

    // prologue: stage tile 0
#pragma unroll
    for (int r = 0; r < 4; r++) {
      const ushort* kg = K + (size_t)(r * 16 + srow) * CDIM + h * HS + sch * 8;
      const ushort* vg = V + (size_t)(r * 16 + srow) * CDIM + h * HS + sch * 8;
      kreg[r] = *(const short8*)kg;
      vreg[r] = *(const short8*)vg;
    }
#pragma unroll
    for (int r = 0; r < 4; r++) {
      *(short8*)((char*)Ks + (((r * 16 + srow) * 16 + schK0) << 4)) = kreg[r];
      *(short8*)((char*)Vs + (((r * 16 + srow) * 16 + schV0) << 4)) = vreg[r];
    }
    __syncthreads();

    for (int t = 0; t < ntile; t++) {
      const int kv0 = t * KVBLK;
      // issue next tile's loads early (latency hides under compute)
      if (t + 1 < ntile) {
        const size_t rb = (size_t)(kv0 + KVBLK + srow) * CDIM + h * HS + sch * 8;
#pragma unroll
        for (int r = 0; r < 4; r++) {
          kreg[r] = *(const short8*)(K + rb + (size_t)r * 16 * CDIM);
          vreg[r] = *(const short8*)(V + rb + (size_t)r * 16 * CDIM);
        }
      }
      const bool active = (kv0 <= qr0 + 31);
      if (active) {
        // ---- S = Q K^T ----
        f32x4 s[2][4];
#pragma unroll
        for (int nt = 0; nt < 4; nt++) {
          const int krow = nt * 16 + llo;
          const char* kr = (const char*)Ks + krow * 256;
          short8 kf[4];
#pragma unroll
          for (int ki = 0; ki < 4; ki++)
            kf[ki] = *(const short8*)(kr + (((ki * 4 + lhi) ^ (krow & 7)) << 4));
          f32x4 s0 = {0.f, 0.f, 0.f, 0.f}, s1 = {0.f, 0.f, 0.f, 0.f};
#pragma unroll
          for (int ki = 0; ki < 4; ki++) {
            s0 = __builtin_amdgcn_mfma_f32_16x16x32_bf16(aq[0][ki], kf[ki], s0, 0, 0, 0);
            s1 = __builtin_amdgcn_mfma_f32_16x16x32_bf16(aq[1][ki], kf[ki], s1, 0, 0, 0);
          }
          s[0][nt] = s0; s[1][nt] = s1;
        }

        // ---- scale + causal mask ----
        const bool needm = (kv0 + KVBLK - 1 > qr0);
#pragma unroll
        for (int mf = 0; mf < 2; mf++) {
#pragma unroll
          for (int nt = 0; nt < 4; nt++) {
            int kvi = kv0 + nt * 16 + llo;
#pragma unroll
            for (int j = 0; j < 4; j++) {
              float sv = s[mf][nt][j] * scale;
              if (needm && kvi > qr0 + mf * 16 + lhi * 4 + j) sv = -1e30f;
              s[mf][nt][j] = sv;
            }
          }
        }

        // ---- online softmax ----
#pragma unroll
        for (int mf = 0; mf < 2; mf++) {
          float sc[4];
#pragma unroll
          for (int j = 0; j < 4; j++) {
            float rm = fmaxf(fmaxf(s[mf][0][j], s[mf][1][j]), fmaxf(s[mf][2][j], s[mf][3][j]));
            rm = fmaxf(rm, __shfl_xor(rm, 1));
            rm = fmaxf(rm, __shfl_xor(rm, 2));
            rm = fmaxf(rm, __shfl_xor(rm, 4));
            rm = fmaxf(rm, __shfl_xor(rm, 8));
            float mn = fmaxf(mrow[mf][j], rm);
            sc[j] = __expf(mrow[mf][j] - mn);
            mrow[mf][j] = mn;
            float rs = 0.f;
#pragma unroll
            for (int nt = 0; nt < 4; nt++) {
              float p = __expf(s[mf][nt][j] - mn);
              s[mf][nt][j] = p;
              rs += p;
            }
            rs += __shfl_xor(rs, 1);
            rs += __shfl_xor(rs, 2);
            rs += __shfl_xor(rs, 4);
            rs += __shfl_xor(rs, 8);
            lrow[mf][j] = lrow[mf][j] * sc[j] + rs;
          }
#pragma unroll
          for (int on = 0; on < 8; on++)
#pragma unroll
            for (int j = 0; j < 4; j++) acc[mf][on][j] *= sc[j];
#pragma unroll
          for (int nt = 0; nt < 4; nt++)
#pragma unroll
            for (int j = 0; j < 4; j++)
              pw[(mf * 16 + lhi * 4 + j) * 72 + nt * 16 + llo] = f2bf(s[mf][nt][j]);
        }

        // ---- O += P V ----
#pragma unroll
        for (int ks = 0; ks < 2; ks++) {
          short8 pf0 = *(const short8*)(pw + (llo) * 72 + ks * 32 + lhi * 8);
          short8 pf1 = *(const short8*)(pw + (16 + llo) * 72 + ks * 32 + lhi * 8);
          short4v vl[8], vh[8];
          if (ks == 0) {
#pragma unroll
            for (int on = 0; on < 8; on++) {
              unsigned a = trbase + (unsigned)(((on * 2) ^ swH) << 4);
              vl[on] = ds_tr16<0>(a);
              vh[on] = ds_tr16<1024>(a);
            }
          } else {
#pragma unroll
            for (int on = 0; on < 8; on++) {
              unsigned a = trbase + (unsigned)(((on * 2) ^ swH) << 4);
              vl[on] = ds_tr16<8192>(a);
              vh[on] = ds_tr16<9216>(a);
            }
          }
          asm volatile("s_waitcnt lgkmcnt(0)" ::: "memory");
          __builtin_amdgcn_sched_barrier(0);
#pragma unroll
          for (int on = 0; on < 8; on++) {
            short8 vf = __builtin_shufflevector(vl[on], vh[on], 0, 1, 2, 3, 4, 5, 6, 7);
            acc[0][on] = __builtin_amdgcn_mfma_f32_16x16x32_bf16(pf0, vf, acc[0][on], 0, 0, 0);
            acc[1][on] = __builtin_amdgcn_mfma_f32_16x16x32_bf16(pf1, vf, acc[1][on], 0, 0, 0);
          }
        }
      }  // active

      __syncthreads();  // all waves done reading Ks/Vs
      if (t + 1 < ntile) {
#pragma unroll
        for (int r = 0; r < 4; r++) {
          *(short8*)((char*)Ks + (((r * 16 + srow) * 16 + schK0) << 4)) = kreg[r];
          *(short8*)((char*)Vs + (((r * 16 + srow) * 16 + schV0) << 4)) = vreg[r];
        }
      }
      __syncthreads();  // staged data visible
    }

    // ---- epilogue for this q-tile ----
    float rinv[2][4];
#pragma unroll
    for (int mf = 0; mf < 2; mf++)
#pragma unroll
      for (int j = 0; j < 4; j++) rinv[mf][j] = 1.0f / lrow[mf][j];
#pragma unroll
    for (int mf = 0; mf < 2; mf++)
#pragma unroll
      for (int on = 0; on < 8; on++)
#pragma unroll
        for (int j = 0; j < 4; j++)
          O[(size_t)(qr0 + mf * 16 + lhi * 4 + j) * CDIM + h * HS + on * 16 + llo] =
              f2bf(acc[mf][on][j] * rinv[mf][j]);
  }  // phase
}

// ---------------- launch ----------------
extern "C" void kernel_launch(void* const* d_in, const int* in_sizes, int n_in,
                              void* d_out, int out_size, void* d_ws, size_t ws_size,
                              hipStream_t stream) {
  const float* hs = (const float*)d_in[0];
  const int* pos = (const int*)d_in[1];
  const float* Wq = (const float*)d_in[2];
  const float* Wk = (const float*)d_in[3];
  const float* Wv = (const float*)d_in[4];
  const float* Wo = (const float*)d_in[5];
  float* out = (float*)d_out;

  const int T = 4096;
  const size_t elems = (size_t)T * CDIM;

  ushort* hsb  = (ushort*)d_ws;      // also reused as attention output
  ushort* wbuf = hsb + elems;        // current weight (bf16), reused 4x
  ushort* qb   = wbuf + elems;
  ushort* kb   = qb + elems;
  ushort* vb   = kb + elems;
  ushort* attn = hsb;

  const int n4 = (int)(elems / 4);
  const int castBlocks = (n4 + 255) / 256;
  dim3 ggrid(32, 32);

  cast_bf16_kernel<<<castBlocks, 256, 0, stream>>>(hs, hsb, n4);

  cast_bf16_kernel<<<castBlocks, 256, 0, stream>>>(Wq, wbuf, n4);
  gemm_bt<ushort><<<ggrid, 256, 0, stream>>>(hsb, wbuf, qb, 4096, 4096, 4096);

  cast_bf16_kernel<<<castBlocks, 256, 0, stream>>>(Wk, wbuf, n4);
  gemm_bt<ushort><<<ggrid, 256, 0, stream>>>(hsb, wbuf, kb, 4096, 4096, 4096);

  cast_bf16_kernel<<<castBlocks, 256, 0, stream>>>(Wv, wbuf, n4);
  gemm_bt<ushort><<<ggrid, 256, 0, stream>>>(hsb, wbuf, vb, 4096, 4096, 4096);

  rope_kernel<<<(T * NH * 64) / 256, 256, 0, stream>>>(qb, kb, pos, T * NH);

  flash_attn<<<dim3(NQT / 2, NH), 256, 0, stream>>>(qb, kb, vb, attn);

  cast_bf16_kernel<<<castBlocks, 256, 0, stream>>>(Wo, wbuf, n4);
  gemm_bt<float><<<ggrid, 256, 0, stream>>>(attn, wbuf, out, 4096, 4096, 4096);
}

// Round 5
// 1102.341 us; speedup vs baseline: 2.0630x; 1.2832x over previous
//
#include <hip/hip_runtime.h>

typedef __attribute__((ext_vector_type(8))) short short8;
typedef __attribute__((ext_vector_type(4))) short short4v;
typedef __attribute__((ext_vector_type(4))) float f32x4;

#define NH 32
#define HS 128
#define CDIM 4096
#define QBLK 128
#define KVBLK 64
#define NQT 32  // T / QBLK

__device__ __forceinline__ ushort f2bf(float f) {
  union { float f; unsigned u; } a; a.f = f;
  unsigned u = a.u;
  return (ushort)((u + 0x7FFFu + ((u >> 16) & 1u)) >> 16);
}
__device__ __forceinline__ float bf2f(ushort h) {
  union { unsigned u; float f; } a; a.u = ((unsigned)h) << 16;
  return a.f;
}

__device__ __forceinline__ void gld16(const void* g, void* l) {
  __builtin_amdgcn_global_load_lds((const __attribute__((address_space(1))) void*)g,
                                   (__attribute__((address_space(3))) void*)l, 16, 0, 0);
}

__device__ __forceinline__ unsigned lds_off(const void* p) {
  return (unsigned)(uintptr_t)(const __attribute__((address_space(3))) void*)p;
}

template<int OFF>
__device__ __forceinline__ short4v ds_tr16(unsigned addr) {
  short4v r;
  asm volatile("ds_read_b64_tr_b16 %0, %1 offset:%c2" : "=v"(r) : "v"(addr), "i"(OFF));
  return r;
}

// ---------------- fp32 -> bf16 cast (vectorized) ----------------
__global__ __launch_bounds__(256) void cast_bf16_kernel(const float* __restrict__ in,
                                                        ushort* __restrict__ out, int n4) {
  int i = blockIdx.x * 256 + threadIdx.x;
  if (i >= n4) return;
  float4 v = ((const float4*)in)[i];
  ushort4 o;
  o.x = f2bf(v.x); o.y = f2bf(v.y); o.z = f2bf(v.z); o.w = f2bf(v.w);
  ((ushort4*)out)[i] = o;
}

// ---------------- GEMM 256x256 8-phase: C[M,N] = A[M,K] @ B[N,K]^T ----------------
// BM=BN=256, BK=64, 8 waves (2Mx4N), 512 thr, LDS 128KiB.
// Panels: A00/A01 = even K-tile rows 0-127 / 128-255; A10/A11 odd; B likewise (rows=cols).
// st_16x32 swizzle, 16B-chunk units: cl = cg ^ (((row>>2)&1)<<1), applied on the global
// source (linear gld_lds dest) and on the ds_read address.
// Wave w: M-group wmg=w>>2 (A panel), N-group wng=w&3 (B panel half + 64-col slice).
// Per iter (2 K-tiles): even tile staged P3(B00) P4(B01,A00) P5(A01); odd staged
// P7(B10,B11) P8(A10,A11). vmcnt(6)@P4 confirms odd tile; vmcnt(8)@P8 confirms even.
#define A00 0
#define A01 16384
#define A10 32768
#define A11 49152
#define B00 65536
#define B01 81920
#define B10 98304
#define B11 114688

template<typename OutT>
__global__ __launch_bounds__(512, 2) void gemm256(const ushort* __restrict__ A,
                                                  const ushort* __restrict__ B,
                                                  OutT* __restrict__ C) {
  __shared__ char sm[131072];
  const int tid = threadIdx.x;
  const int w = tid >> 6, lane = tid & 63, lhi = lane >> 4, llo = lane & 15;

  // XCD-aware swizzle (256 blocks, 8 XCDs, bijective)
  const int bid = blockIdx.x;
  const int x = (bid & 7) * 32 + (bid >> 3);
  const int mt = x >> 4, nt = x & 15;
  const size_t m0 = (size_t)mt * 256, n0 = (size_t)nt * 256;

  const char* A0p = (const char*)(A + m0 * 4096);            // rows 0-127
  const char* A1p = A0p + 1048576;                           // rows 128-255
  const char* B0p = (const char*)(B + n0 * 4096);            // cols 0-127
  const char* B1p = B0p + 1048576;                           // cols 128-255

  // staging offsets: thread covers (row ri, chunk slot i&7); global chunk = slot ^ swz(row)
  const int i0 = tid, i1 = tid + 512;
  const int ri0 = i0 >> 3, ri1 = i1 >> 3;
  const int cg0 = (i0 & 7) ^ (((ri0 >> 2) & 1) << 1);
  const int cg1 = (i1 & 7) ^ (((ri1 >> 2) & 1) << 1);
  const int off0 = ri0 * 8192 + cg0 * 16;
  const int off1 = ri1 * 8192 + cg1 * 16;
  const unsigned sd0 = (unsigned)(w * 1024);
  const unsigned sd1 = (unsigned)(8192 + w * 1024);

  // ds_read offsets (row=llo within 16-row frag, chunk = kk*4+lhi, swizzled)
  const int sw = ((llo >> 2) & 1) << 1;
  const unsigned rd0 = (unsigned)((llo * 8 + ((0 * 4 + lhi) ^ sw)) * 16);
  const unsigned rd1 = (unsigned)((llo * 8 + ((1 * 4 + lhi) ^ sw)) * 16);

  // per-wave panel selection
  const int wmg = w >> 2, wng = w & 3;
  const unsigned aE = wmg ? A01 : A00;
  const unsigned aO = wmg ? A11 : A10;
  const unsigned bE = (wng >> 1) ? B01 : B00;
  const unsigned bO = (wng >> 1) ? B11 : B10;
  const unsigned bco = (unsigned)((wng & 1) * 8192);  // 64 cols * 128 B

  f32x4 acc[8][4] = {};
  short8 a0[4], a1[4], u0[2], u1[2], v0[2], v1[2];

#define STG(PAN, K0, LB) do { \
    gld16((PAN) + (size_t)(K0) * 2 + off0, sm + (LB) + sd0); \
    gld16((PAN) + (size_t)(K0) * 2 + off1, sm + (LB) + sd1); \
  } while (0)
#define LDA(BASE, MQ) do { _Pragma("unroll") for (int m_ = 0; m_ < 4; m_++) { \
    a0[m_] = *(const short8*)(sm + (BASE) + (MQ) * 8192 + m_ * 2048 + rd0); \
    a1[m_] = *(const short8*)(sm + (BASE) + (MQ) * 8192 + m_ * 2048 + rd1); } } while (0)
#define LDB(R0, R1, BASE, NQ) do { _Pragma("unroll") for (int n_ = 0; n_ < 2; n_++) { \
    R0[n_] = *(const short8*)(sm + (BASE) + bco + (NQ) * 4096 + n_ * 2048 + rd0); \
    R1[n_] = *(const short8*)(sm + (BASE) + bco + (NQ) * 4096 + n_ * 2048 + rd1); } } while (0)
#define MM(MQ, NQ, R0, R1) do { \
    _Pragma("unroll") for (int m_ = 0; m_ < 4; m_++) _Pragma("unroll") for (int n_ = 0; n_ < 2; n_++) \
      acc[(MQ) * 4 + m_][(NQ) * 2 + n_] = __builtin_amdgcn_mfma_f32_16x16x32_bf16(a0[m_], R0[n_], acc[(MQ) * 4 + m_][(NQ) * 2 + n_], 0, 0, 0); \
    _Pragma("unroll") for (int m_ = 0; m_ < 4; m_++) _Pragma("unroll") for (int n_ = 0; n_ < 2; n_++) \
      acc[(MQ) * 4 + m_][(NQ) * 2 + n_] = __builtin_amdgcn_mfma_f32_16x16x32_bf16(a1[m_], R1[n_], acc[(MQ) * 4 + m_][(NQ) * 2 + n_], 0, 0, 0); \
  } while (0)
#define BAR1 do { __builtin_amdgcn_s_barrier(); \
    asm volatile("s_waitcnt lgkmcnt(0)" ::: "memory"); \
    __builtin_amdgcn_sched_barrier(0); \
    __builtin_amdgcn_s_setprio(1); } while (0)
#define BAR2 do { __builtin_amdgcn_s_setprio(0); __builtin_amdgcn_s_barrier(); \
    __builtin_amdgcn_sched_barrier(0); } while (0)

  // prologue: tile0 (k=0) then tile1 (k=64); confirm tile0
  STG(B0p, 0, B00); STG(B1p, 0, B01); STG(A0p, 0, A00); STG(A1p, 0, A01);
  STG(B0p, 64, B10); STG(B1p, 64, B11); STG(A0p, 64, A10); STG(A1p, 64, A11);
  asm volatile("s_waitcnt vmcnt(8)" ::: "memory");
  __builtin_amdgcn_s_barrier();
  __builtin_amdgcn_sched_barrier(0);

  for (int it = 0; it < 32; ++it) {
    const int kc = it * 128;
    const bool st = (it < 31);
    // P1: quadrant (m0,n0) of even tile
    LDA(aE, 0); LDB(u0, u1, bE, 0);
    BAR1; MM(0, 0, u0, u1); BAR2;
    // P2: (m0,n1)
    LDB(v0, v1, bE, 1);
    BAR1; MM(0, 1, v0, v1); BAR2;
    // P3: (m1,n1); stage even.B00 (B cols 0-127 read last at P2)
    LDA(aE, 1);
    if (st) STG(B0p, kc + 128, B00);
    BAR1; MM(1, 1, v0, v1); BAR2;
    // P4: (m1,n0); stage even.B01 + even.A00; confirm odd tile (vmcnt 6)
    if (st) { STG(B1p, kc + 128, B01); STG(A0p, kc + 128, A00); }
    BAR1; MM(1, 0, u0, u1);
    __builtin_amdgcn_s_setprio(0);
    if (st) asm volatile("s_waitcnt vmcnt(6)" ::: "memory");
    else    asm volatile("s_waitcnt vmcnt(0)" ::: "memory");
    __builtin_amdgcn_s_barrier();
    __builtin_amdgcn_sched_barrier(0);
    // P5: quadrant (m0,n0) of odd tile; stage even.A01
    LDA(aO, 0); LDB(u0, u1, bO, 0);
    if (st) STG(A1p, kc + 128, A01);
    BAR1; MM(0, 0, u0, u1); BAR2;
    // P6: (m0,n1)
    LDB(v0, v1, bO, 1);
    BAR1; MM(0, 1, v0, v1); BAR2;
    // P7: (m1,n1); stage odd.B10 + odd.B11 (B read last at P6)
    LDA(aO, 1);
    if (st) { STG(B0p, kc + 192, B10); STG(B1p, kc + 192, B11); }
    BAR1; MM(1, 1, v0, v1); BAR2;
    // P8: (m1,n0); stage odd.A10 + odd.A11; confirm even tile (vmcnt 8)
    if (st) { STG(A0p, kc + 192, A10); STG(A1p, kc + 192, A11); }
    BAR1; MM(1, 0, u0, u1);
    __builtin_amdgcn_s_setprio(0);
    if (st) asm volatile("s_waitcnt vmcnt(8)" ::: "memory");
    __builtin_amdgcn_s_barrier();
    __builtin_amdgcn_sched_barrier(0);
  }

  // epilogue: C write
  const int wm = wmg * 128, wn = wng * 64;
#pragma unroll
  for (int m = 0; m < 8; m++) {
#pragma unroll
    for (int nf = 0; nf < 4; nf++) {
      const size_t col = n0 + wn + nf * 16 + llo;
#pragma unroll
      for (int j = 0; j < 4; j++) {
        const size_t row = m0 + wm + m * 16 + lhi * 4 + j;
        if constexpr (sizeof(OutT) == 4)
          C[row * 4096 + col] = acc[m][nf][j];
        else
          C[row * 4096 + col] = f2bf(acc[m][nf][j]);
      }
    }
  }
#undef STG
#undef LDA
#undef LDB
#undef MM
#undef BAR1
#undef BAR2
}

// ---------------- RoPE (in-place on Q and K, bf16) ----------------
__global__ __launch_bounds__(256) void rope_kernel(ushort* __restrict__ Q,
                                                   ushort* __restrict__ Kb,
                                                   const int* __restrict__ pos_ids,
                                                   int nrows) {
  int gid = blockIdx.x * 256 + threadIdx.x;
  int d = gid & 63;
  int row = gid >> 6;
  if (row >= nrows) return;
  int t = row >> 5;
  int pos = pos_ids[t];
  float inv = expf((float)d * -0.14391156831212788f);  // -ln(10000)/64
  float ang = (float)pos * inv;
  float s, c;
  sincosf(ang, &s, &c);
  size_t base = (size_t)row * HS;
  {
    float x1 = bf2f(Q[base + d]), x2 = bf2f(Q[base + d + 64]);
    Q[base + d]      = f2bf(x1 * c - x2 * s);
    Q[base + d + 64] = f2bf(x2 * c + x1 * s);
  }
  {
    float x1 = bf2f(Kb[base + d]), x2 = bf2f(Kb[base + d + 64]);
    Kb[base + d]      = f2bf(x1 * c - x2 * s);
    Kb[base + d + 64] = f2bf(x2 * c + x1 * s);
  }
}

// ---------------- Causal flash attention (v3, unchanged from passing round) ----------------
__global__ __launch_bounds__(256) void flash_attn(const ushort* __restrict__ Q,
                                                  const ushort* __restrict__ K,
                                                  const ushort* __restrict__ V,
                                                  ushort* __restrict__ O) {
  __shared__ ushort Ks[KVBLK * HS];
  __shared__ ushort Vs[KVBLK * HS];
  __shared__ ushort Ps[4][32 * 72];   // per-wave P tile, stride 72 (pad +8)
  const int tid = threadIdx.x;
  const int w = tid >> 6, l = tid & 63, lhi = l >> 4, llo = l & 15;
  const int qbp = blockIdx.x, h = blockIdx.y;

  // tr-read per-lane constants (V path)
  const int g = llo >> 2, c = llo & 3;
  const int swz = g | ((lhi & 1) << 2);
  const int c1 = c >> 1;
  const int swL = swz & 1, swH = swz & 6;
  const unsigned trbase = lds_off(Vs) + (unsigned)((lhi * 8 + g) * 256 + ((c1 ^ swL) << 4) + (c & 1) * 8);

  // staging per-lane constants
  const int srow = tid >> 4, sch = tid & 15;   // +16 rows per round
  const int schK0 = sch ^ (srow & 7);
  const int schV0 = sch ^ ((srow & 3) | (((srow >> 3) & 1) << 2));

  ushort* pw = Ps[w];
  const float scale = 0.08838834764831845f;  // 1/sqrt(128)

  short8 kreg[4], vreg[4];

  for (int ph = 0; ph < 2; ph++) {
    const int qt = ph ? (NQT - 1 - qbp) : qbp;
    const int qr0 = qt * QBLK + w * 32;
    const int ntile = 2 * qt + 2;

    short8 aq[2][4];
#pragma unroll
    for (int mf = 0; mf < 2; mf++) {
      const ushort* qp = Q + (size_t)(qr0 + mf * 16 + llo) * CDIM + h * HS + lhi * 8;
#pragma unroll
      for (int ki = 0; ki < 4; ki++) aq[mf][ki] = *(const short8*)(qp + ki * 32);
    }

    f32x4 acc[2][8] = {};
    f32x4 mrow[2], lrow[2];
#pragma unroll
    for (int mf = 0; mf < 2; mf++) {
#pragma unroll
      for (int j = 0; j < 4; j++) { mrow[mf][j] = -1e30f; lrow[mf][j] = 0.f; }
    }

    // prologue: stage tile 0
#pragma unroll
    for (int r = 0; r < 4; r++) {
      const ushort* kg = K + (size_t)(r * 16 + srow) * CDIM + h * HS + sch * 8;
      const ushort* vg = V + (size_t)(r * 16 + srow) * CDIM + h * HS + sch * 8;
      kreg[r] = *(const short8*)kg;
      vreg[r] = *(const short8*)vg;
    }
#pragma unroll
    for (int r = 0; r < 4; r++) {
      *(short8*)((char*)Ks + (((r * 16 + srow) * 16 + schK0) << 4)) = kreg[r];
      *(short8*)((char*)Vs + (((r * 16 + srow) * 16 + schV0) << 4)) = vreg[r];
    }
    __syncthreads();

    for (int t = 0; t < ntile; t++) {
      const int kv0 = t * KVBLK;
      if (t + 1 < ntile) {
        const size_t rb = (size_t)(kv0 + KVBLK + srow) * CDIM + h * HS + sch * 8;
#pragma unroll
        for (int r = 0; r < 4; r++) {
          kreg[r] = *(const short8*)(K + rb + (size_t)r * 16 * CDIM);
          vreg[r] = *(const short8*)(V + rb + (size_t)r * 16 * CDIM);
        }
      }
      const bool active = (kv0 <= qr0 + 31);
      if (active) {
        // ---- S = Q K^T ----
        f32x4 s[2][4];
#pragma unroll
        for (int nt = 0; nt < 4; nt++) {
          const int krow = nt * 16 + llo;
          const char* kr = (const char*)Ks + krow * 256;
          short8 kf[4];
#pragma unroll
          for (int ki = 0; ki < 4; ki++)
            kf[ki] = *(const short8*)(kr + (((ki * 4 + lhi) ^ (krow & 7)) << 4));
          f32x4 s0 = {0.f, 0.f, 0.f, 0.f}, s1 = {0.f, 0.f, 0.f, 0.f};
#pragma unroll
          for (int ki = 0; ki < 4; ki++) {
            s0 = __builtin_amdgcn_mfma_f32_16x16x32_bf16(aq[0][ki], kf[ki], s0, 0, 0, 0);
            s1 = __builtin_amdgcn_mfma_f32_16x16x32_bf16(aq[1][ki], kf[ki], s1, 0, 0, 0);
          }
          s[0][nt] = s0; s[1][nt] = s1;
        }

        const bool needm = (kv0 + KVBLK - 1 > qr0);
#pragma unroll
        for (int mf = 0; mf < 2; mf++) {
#pragma unroll
          for (int nt = 0; nt < 4; nt++) {
            int kvi = kv0 + nt * 16 + llo;
#pragma unroll
            for (int j = 0; j < 4; j++) {
              float sv = s[mf][nt][j] * scale;
              if (needm && kvi > qr0 + mf * 16 + lhi * 4 + j) sv = -1e30f;
              s[mf][nt][j] = sv;
            }
          }
        }

#pragma unroll
        for (int mf = 0; mf < 2; mf++) {
          float sc[4];
#pragma unroll
          for (int j = 0; j < 4; j++) {
            float rm = fmaxf(fmaxf(s[mf][0][j], s[mf][1][j]), fmaxf(s[mf][2][j], s[mf][3][j]));
            rm = fmaxf(rm, __shfl_xor(rm, 1));
            rm = fmaxf(rm, __shfl_xor(rm, 2));
            rm = fmaxf(rm, __shfl_xor(rm, 4));
            rm = fmaxf(rm, __shfl_xor(rm, 8));
            float mn = fmaxf(mrow[mf][j], rm);
            sc[j] = __expf(mrow[mf][j] - mn);
            mrow[mf][j] = mn;
            float rs = 0.f;
#pragma unroll
            for (int nt = 0; nt < 4; nt++) {
              float p = __expf(s[mf][nt][j] - mn);
              s[mf][nt][j] = p;
              rs += p;
            }
            rs += __shfl_xor(rs, 1);
            rs += __shfl_xor(rs, 2);
            rs += __shfl_xor(rs, 4);
            rs += __shfl_xor(rs, 8);
            lrow[mf][j] = lrow[mf][j] * sc[j] + rs;
          }
#pragma unroll
          for (int on = 0; on < 8; on++)
#pragma unroll
            for (int j = 0; j < 4; j++) acc[mf][on][j] *= sc[j];
#pragma unroll
          for (int nt = 0; nt < 4; nt++)
#pragma unroll
            for (int j = 0; j < 4; j++)
              pw[(mf * 16 + lhi * 4 + j) * 72 + nt * 16 + llo] = f2bf(s[mf][nt][j]);
        }

        // ---- O += P V ----
#pragma unroll
        for (int ks = 0; ks < 2; ks++) {
          short8 pf0 = *(const short8*)(pw + (llo) * 72 + ks * 32 + lhi * 8);
          short8 pf1 = *(const short8*)(pw + (16 + llo) * 72 + ks * 32 + lhi * 8);
          short4v vl[8], vh[8];
          if (ks == 0) {
#pragma unroll
            for (int on = 0; on < 8; on++) {
              unsigned a = trbase + (unsigned)(((on * 2) ^ swH) << 4);
              vl[on] = ds_tr16<0>(a);
              vh[on] = ds_tr16<1024>(a);
            }
          } else {
#pragma unroll
            for (int on = 0; on < 8; on++) {
              unsigned a = trbase + (unsigned)(((on * 2) ^ swH) << 4);
              vl[on] = ds_tr16<8192>(a);
              vh[on] = ds_tr16<9216>(a);
            }
          }
          asm volatile("s_waitcnt lgkmcnt(0)" ::: "memory");
          __builtin_amdgcn_sched_barrier(0);
#pragma unroll
          for (int on = 0; on < 8; on++) {
            short8 vf = __builtin_shufflevector(vl[on], vh[on], 0, 1, 2, 3, 4, 5, 6, 7);
            acc[0][on] = __builtin_amdgcn_mfma_f32_16x16x32_bf16(pf0, vf, acc[0][on], 0, 0, 0);
            acc[1][on] = __builtin_amdgcn_mfma_f32_16x16x32_bf16(pf1, vf, acc[1][on], 0, 0, 0);
          }
        }
      }  // active

      __syncthreads();
      if (t + 1 < ntile) {
#pragma unroll
        for (int r = 0; r < 4; r++) {
          *(short8*)((char*)Ks + (((r * 16 + srow) * 16 + schK0) << 4)) = kreg[r];
          *(short8*)((char*)Vs + (((r * 16 + srow) * 16 + schV0) << 4)) = vreg[r];
        }
      }
      __syncthreads();
    }

    // ---- epilogue for this q-tile ----
    float rinv[2][4];
#pragma unroll
    for (int mf = 0; mf < 2; mf++)
#pragma unroll
      for (int j = 0; j < 4; j++) rinv[mf][j] = 1.0f / lrow[mf][j];
#pragma unroll
    for (int mf = 0; mf < 2; mf++)
#pragma unroll
      for (int on = 0; on < 8; on++)
#pragma unroll
        for (int j = 0; j < 4; j++)
          O[(size_t)(qr0 + mf * 16 + lhi * 4 + j) * CDIM + h * HS + on * 16 + llo] =
              f2bf(acc[mf][on][j] * rinv[mf][j]);
  }  // phase
}

// ---------------- launch ----------------
extern "C" void kernel_launch(void* const* d_in, const int* in_sizes, int n_in,
                              void* d_out, int out_size, void* d_ws, size_t ws_size,
                              hipStream_t stream) {
  const float* hs = (const float*)d_in[0];
  const int* pos = (const int*)d_in[1];
  const float* Wq = (const float*)d_in[2];
  const float* Wk = (const float*)d_in[3];
  const float* Wv = (const float*)d_in[4];
  const float* Wo = (const float*)d_in[5];
  float* out = (float*)d_out;

  const int T = 4096;
  const size_t elems = (size_t)T * CDIM;

  ushort* hsb  = (ushort*)d_ws;      // also reused as attention output
  ushort* wbuf = hsb + elems;        // current weight (bf16), reused 4x
  ushort* qb   = wbuf + elems;
  ushort* kb   = qb + elems;
  ushort* vb   = kb + elems;
  ushort* attn = hsb;

  const int n4 = (int)(elems / 4);
  const int castBlocks = (n4 + 255) / 256;

  cast_bf16_kernel<<<castBlocks, 256, 0, stream>>>(hs, hsb, n4);

  cast_bf16_kernel<<<castBlocks, 256, 0, stream>>>(Wq, wbuf, n4);
  gemm256<ushort><<<256, 512, 0, stream>>>(hsb, wbuf, qb);

  cast_bf16_kernel<<<castBlocks, 256, 0, stream>>>(Wk, wbuf, n4);
  gemm256<ushort><<<256, 512, 0, stream>>>(hsb, wbuf, kb);

  cast_bf16_kernel<<<castBlocks, 256, 0, stream>>>(Wv, wbuf, n4);
  gemm256<ushort><<<256, 512, 0, stream>>>(hsb, wbuf, vb);

  rope_kernel<<<(T * NH * 64) / 256, 256, 0, stream>>>(qb, kb, pos, T * NH);

  flash_attn<<<dim3(NQT / 2, NH), 256, 0, stream>>>(qb, kb, vb, attn);

  cast_bf16_kernel<<<castBlocks, 256, 0, stream>>>(Wo, wbuf, n4);
  gemm256<float><<<256, 512, 0, stream>>>(attn, wbuf, out);
}

// Round 6
// 968.258 us; speedup vs baseline: 2.3487x; 1.1385x over previous
//
#include <hip/hip_runtime.h>

typedef __attribute__((ext_vector_type(8))) short short8;
typedef __attribute__((ext_vector_type(4))) short short4v;
typedef __attribute__((ext_vector_type(4))) float f32x4;

#define NH 32
#define HS 128
#define CDIM 4096
#define QBLK 128
#define KVBLK 64
#define NQT 32  // T / QBLK

__device__ __forceinline__ ushort f2bf(float f) {
  union { float f; unsigned u; } a; a.f = f;
  unsigned u = a.u;
  return (ushort)((u + 0x7FFFu + ((u >> 16) & 1u)) >> 16);
}
__device__ __forceinline__ float bf2f(ushort h) {
  union { unsigned u; float f; } a; a.u = ((unsigned)h) << 16;
  return a.f;
}
__device__ __forceinline__ unsigned cvtpk_bf16(float lo, float hi) {
  unsigned r;
  asm("v_cvt_pk_bf16_f32 %0, %1, %2" : "=v"(r) : "v"(lo), "v"(hi));
  return r;
}

__device__ __forceinline__ void gld16(const void* g, void* l) {
  __builtin_amdgcn_global_load_lds((const __attribute__((address_space(1))) void*)g,
                                   (__attribute__((address_space(3))) void*)l, 16, 0, 0);
}

__device__ __forceinline__ unsigned lds_off(const void* p) {
  return (unsigned)(uintptr_t)(const __attribute__((address_space(3))) void*)p;
}

template<int OFF>
__device__ __forceinline__ short4v ds_tr16(unsigned addr) {
  short4v r;
  asm volatile("ds_read_b64_tr_b16 %0, %1 offset:%c2" : "=v"(r) : "v"(addr), "i"(OFF));
  return r;
}

// ---------------- fp32 -> bf16 cast (vectorized) ----------------
__global__ __launch_bounds__(256) void cast_bf16_kernel(const float* __restrict__ in,
                                                        ushort* __restrict__ out, int n4) {
  int i = blockIdx.x * 256 + threadIdx.x;
  if (i >= n4) return;
  float4 v = ((const float4*)in)[i];
  ushort4 o;
  o.x = f2bf(v.x); o.y = f2bf(v.y); o.z = f2bf(v.z); o.w = f2bf(v.w);
  ((ushort4*)out)[i] = o;
}

// ---------------- GEMM 256x256 8-phase (unchanged, verified round 5) ----------------
#define A00 0
#define A01 16384
#define A10 32768
#define A11 49152
#define B00 65536
#define B01 81920
#define B10 98304
#define B11 114688

template<typename OutT>
__global__ __launch_bounds__(512, 2) void gemm256(const ushort* __restrict__ A,
                                                  const ushort* __restrict__ B,
                                                  OutT* __restrict__ C) {
  __shared__ char sm[131072];
  const int tid = threadIdx.x;
  const int w = tid >> 6, lane = tid & 63, lhi = lane >> 4, llo = lane & 15;

  const int bid = blockIdx.x;
  const int x = (bid & 7) * 32 + (bid >> 3);
  const int mt = x >> 4, nt = x & 15;
  const size_t m0 = (size_t)mt * 256, n0 = (size_t)nt * 256;

  const char* A0p = (const char*)(A + m0 * 4096);
  const char* A1p = A0p + 1048576;
  const char* B0p = (const char*)(B + n0 * 4096);
  const char* B1p = B0p + 1048576;

  const int i0 = tid, i1 = tid + 512;
  const int ri0 = i0 >> 3, ri1 = i1 >> 3;
  const int cg0 = (i0 & 7) ^ (((ri0 >> 2) & 1) << 1);
  const int cg1 = (i1 & 7) ^ (((ri1 >> 2) & 1) << 1);
  const int off0 = ri0 * 8192 + cg0 * 16;
  const int off1 = ri1 * 8192 + cg1 * 16;
  const unsigned sd0 = (unsigned)(w * 1024);
  const unsigned sd1 = (unsigned)(8192 + w * 1024);

  const int sw = ((llo >> 2) & 1) << 1;
  const unsigned rd0 = (unsigned)((llo * 8 + ((0 * 4 + lhi) ^ sw)) * 16);
  const unsigned rd1 = (unsigned)((llo * 8 + ((1 * 4 + lhi) ^ sw)) * 16);

  const int wmg = w >> 2, wng = w & 3;
  const unsigned aE = wmg ? A01 : A00;
  const unsigned aO = wmg ? A11 : A10;
  const unsigned bE = (wng >> 1) ? B01 : B00;
  const unsigned bO = (wng >> 1) ? B11 : B10;
  const unsigned bco = (unsigned)((wng & 1) * 8192);

  f32x4 acc[8][4] = {};
  short8 a0[4], a1[4], u0[2], u1[2], v0[2], v1[2];

#define STG(PAN, K0, LB) do { \
    gld16((PAN) + (size_t)(K0) * 2 + off0, sm + (LB) + sd0); \
    gld16((PAN) + (size_t)(K0) * 2 + off1, sm + (LB) + sd1); \
  } while (0)
#define LDA(BASE, MQ) do { _Pragma("unroll") for (int m_ = 0; m_ < 4; m_++) { \
    a0[m_] = *(const short8*)(sm + (BASE) + (MQ) * 8192 + m_ * 2048 + rd0); \
    a1[m_] = *(const short8*)(sm + (BASE) + (MQ) * 8192 + m_ * 2048 + rd1); } } while (0)
#define LDB(R0, R1, BASE, NQ) do { _Pragma("unroll") for (int n_ = 0; n_ < 2; n_++) { \
    R0[n_] = *(const short8*)(sm + (BASE) + bco + (NQ) * 4096 + n_ * 2048 + rd0); \
    R1[n_] = *(const short8*)(sm + (BASE) + bco + (NQ) * 4096 + n_ * 2048 + rd1); } } while (0)
#define MM(MQ, NQ, R0, R1) do { \
    _Pragma("unroll") for (int m_ = 0; m_ < 4; m_++) _Pragma("unroll") for (int n_ = 0; n_ < 2; n_++) \
      acc[(MQ) * 4 + m_][(NQ) * 2 + n_] = __builtin_amdgcn_mfma_f32_16x16x32_bf16(a0[m_], R0[n_], acc[(MQ) * 4 + m_][(NQ) * 2 + n_], 0, 0, 0); \
    _Pragma("unroll") for (int m_ = 0; m_ < 4; m_++) _Pragma("unroll") for (int n_ = 0; n_ < 2; n_++) \
      acc[(MQ) * 4 + m_][(NQ) * 2 + n_] = __builtin_amdgcn_mfma_f32_16x16x32_bf16(a1[m_], R1[n_], acc[(MQ) * 4 + m_][(NQ) * 2 + n_], 0, 0, 0); \
  } while (0)
#define BAR1 do { __builtin_amdgcn_s_barrier(); \
    asm volatile("s_waitcnt lgkmcnt(0)" ::: "memory"); \
    __builtin_amdgcn_sched_barrier(0); \
    __builtin_amdgcn_s_setprio(1); } while (0)
#define BAR2 do { __builtin_amdgcn_s_setprio(0); __builtin_amdgcn_s_barrier(); \
    __builtin_amdgcn_sched_barrier(0); } while (0)

  STG(B0p, 0, B00); STG(B1p, 0, B01); STG(A0p, 0, A00); STG(A1p, 0, A01);
  STG(B0p, 64, B10); STG(B1p, 64, B11); STG(A0p, 64, A10); STG(A1p, 64, A11);
  asm volatile("s_waitcnt vmcnt(8)" ::: "memory");
  __builtin_amdgcn_s_barrier();
  __builtin_amdgcn_sched_barrier(0);

  for (int it = 0; it < 32; ++it) {
    const int kc = it * 128;
    const bool st = (it < 31);
    LDA(aE, 0); LDB(u0, u1, bE, 0);
    BAR1; MM(0, 0, u0, u1); BAR2;
    LDB(v0, v1, bE, 1);
    BAR1; MM(0, 1, v0, v1); BAR2;
    LDA(aE, 1);
    if (st) STG(B0p, kc + 128, B00);
    BAR1; MM(1, 1, v0, v1); BAR2;
    if (st) { STG(B1p, kc + 128, B01); STG(A0p, kc + 128, A00); }
    BAR1; MM(1, 0, u0, u1);
    __builtin_amdgcn_s_setprio(0);
    if (st) asm volatile("s_waitcnt vmcnt(6)" ::: "memory");
    else    asm volatile("s_waitcnt vmcnt(0)" ::: "memory");
    __builtin_amdgcn_s_barrier();
    __builtin_amdgcn_sched_barrier(0);
    LDA(aO, 0); LDB(u0, u1, bO, 0);
    if (st) STG(A1p, kc + 128, A01);
    BAR1; MM(0, 0, u0, u1); BAR2;
    LDB(v0, v1, bO, 1);
    BAR1; MM(0, 1, v0, v1); BAR2;
    LDA(aO, 1);
    if (st) { STG(B0p, kc + 192, B10); STG(B1p, kc + 192, B11); }
    BAR1; MM(1, 1, v0, v1); BAR2;
    if (st) { STG(A0p, kc + 192, A10); STG(A1p, kc + 192, A11); }
    BAR1; MM(1, 0, u0, u1);
    __builtin_amdgcn_s_setprio(0);
    if (st) asm volatile("s_waitcnt vmcnt(8)" ::: "memory");
    __builtin_amdgcn_s_barrier();
    __builtin_amdgcn_sched_barrier(0);
  }

  const int wm = wmg * 128, wn = wng * 64;
#pragma unroll
  for (int m = 0; m < 8; m++) {
#pragma unroll
    for (int nf = 0; nf < 4; nf++) {
      const size_t col = n0 + wn + nf * 16 + llo;
#pragma unroll
      for (int j = 0; j < 4; j++) {
        const size_t row = m0 + wm + m * 16 + lhi * 4 + j;
        if constexpr (sizeof(OutT) == 4)
          C[row * 4096 + col] = acc[m][nf][j];
        else
          C[row * 4096 + col] = f2bf(acc[m][nf][j]);
      }
    }
  }
#undef STG
#undef LDA
#undef LDB
#undef MM
#undef BAR1
#undef BAR2
}

// ---------------- RoPE (in-place on Q and K, bf16) ----------------
__global__ __launch_bounds__(256) void rope_kernel(ushort* __restrict__ Q,
                                                   ushort* __restrict__ Kb,
                                                   const int* __restrict__ pos_ids,
                                                   int nrows) {
  int gid = blockIdx.x * 256 + threadIdx.x;
  int d = gid & 63;
  int row = gid >> 6;
  if (row >= nrows) return;
  int t = row >> 5;
  int pos = pos_ids[t];
  float inv = expf((float)d * -0.14391156831212788f);  // -ln(10000)/64
  float ang = (float)pos * inv;
  float s, c;
  sincosf(ang, &s, &c);
  size_t base = (size_t)row * HS;
  {
    float x1 = bf2f(Q[base + d]), x2 = bf2f(Q[base + d + 64]);
    Q[base + d]      = f2bf(x1 * c - x2 * s);
    Q[base + d + 64] = f2bf(x2 * c + x1 * s);
  }
  {
    float x1 = bf2f(Kb[base + d]), x2 = bf2f(Kb[base + d + 64]);
    Kb[base + d]      = f2bf(x1 * c - x2 * s);
    Kb[base + d + 64] = f2bf(x2 * c + x1 * s);
  }
}

// ---------------- Causal flash attention (v4: swapped QK^T, in-register softmax) ----------------
// grid (NQT/2, NH); block (qb,h) processes q-tiles {qb, NQT-1-qb}. 4 waves, wave owns 32 q-rows.
// S^T = K Q^T (operand-swapped MFMA): lane holds one q-row's 16 S-values per mf ->
// row softmax = in-register reduce + 2 shfl. P^T packed via v_cvt_pk_bf16_f32,
// stored [32 q][64 kv] (144B row stride), read back as ds_read_b128 B-frags.
// PV: O^T = V^T P^T; V^T A-frags via ds_read_b64_tr_b16 (same reads as v3).
// Defer-max (T13, THR=8): skip O-rescale when max grows <= 8.
__global__ __launch_bounds__(256) void flash_attn(const ushort* __restrict__ Q,
                                                  const ushort* __restrict__ K,
                                                  const ushort* __restrict__ V,
                                                  ushort* __restrict__ O) {
  __shared__ __align__(16) ushort Ks[KVBLK * HS];
  __shared__ __align__(16) ushort Vs[KVBLK * HS];
  __shared__ __align__(16) ushort Ps[4][32 * 72];   // per-wave P^T tile: 32 rows x 144 B
  const int tid = threadIdx.x;
  const int w = tid >> 6, l = tid & 63, lhi = l >> 4, llo = l & 15;
  const int qbp = blockIdx.x, h = blockIdx.y;

  // tr-read per-lane constants (V path, unchanged from v3)
  const int g = llo >> 2, c = llo & 3;
  const int swz = g | ((lhi & 1) << 2);
  const int c1 = c >> 1;
  const int swL = swz & 1, swH = swz & 6;
  const unsigned trbase = lds_off(Vs) + (unsigned)((lhi * 8 + g) * 256 + ((c1 ^ swL) << 4) + (c & 1) * 8);

  // staging per-lane constants (unchanged)
  const int srow = tid >> 4, sch = tid & 15;
  const int schK0 = sch ^ (srow & 7);
  const int schV0 = sch ^ ((srow & 3) | (((srow >> 3) & 1) << 2));

  char* pwB = (char*)Ps[w];
  const float scale = 0.08838834764831845f;  // 1/sqrt(128)

  short8 kreg[4], vreg[4];

  for (int ph = 0; ph < 2; ph++) {
    const int qt = ph ? (NQT - 1 - qbp) : qbp;
    const int qr0 = qt * QBLK + w * 32;
    const int ntile = 2 * qt + 2;

    short8 aq[2][4];
#pragma unroll
    for (int mf = 0; mf < 2; mf++) {
      const ushort* qp = Q + (size_t)(qr0 + mf * 16 + llo) * CDIM + h * HS + lhi * 8;
#pragma unroll
      for (int ki = 0; ki < 4; ki++) aq[mf][ki] = *(const short8*)(qp + ki * 32);
    }

    f32x4 acc[2][8] = {};
    float mrow[2] = {-1e30f, -1e30f};
    float lrow[2] = {0.f, 0.f};

    // prologue: stage tile 0
#pragma unroll
    for (int r = 0; r < 4; r++) {
      const ushort* kg = K + (size_t)(r * 16 + srow) * CDIM + h * HS + sch * 8;
      const ushort* vg = V + (size_t)(r * 16 + srow) * CDIM + h * HS + sch * 8;
      kreg[r] = *(const short8*)kg;
      vreg[r] = *(const short8*)vg;
    }
#pragma unroll
    for (int r = 0; r < 4; r++) {
      *(short8*)((char*)Ks + (((r * 16 + srow) * 16 + schK0) << 4)) = kreg[r];
      *(short8*)((char*)Vs + (((r * 16 + srow) * 16 + schV0) << 4)) = vreg[r];
    }
    __syncthreads();

    for (int t = 0; t < ntile; t++) {
      const int kv0 = t * KVBLK;
      if (t + 1 < ntile) {
        const size_t rb = (size_t)(kv0 + KVBLK + srow) * CDIM + h * HS + sch * 8;
#pragma unroll
        for (int r = 0; r < 4; r++) {
          kreg[r] = *(const short8*)(K + rb + (size_t)r * 16 * CDIM);
          vreg[r] = *(const short8*)(V + rb + (size_t)r * 16 * CDIM);
        }
      }
      const bool active = (kv0 <= qr0 + 31);
      if (active) {
        // ---- S^T = K Q^T  (swapped operands; same LDS reads as v3) ----
        f32x4 s[2][4];
#pragma unroll
        for (int nt = 0; nt < 4; nt++) {
          const int krow = nt * 16 + llo;
          const char* kr = (const char*)Ks + krow * 256;
          short8 kf[4];
#pragma unroll
          for (int ki = 0; ki < 4; ki++)
            kf[ki] = *(const short8*)(kr + (((ki * 4 + lhi) ^ (krow & 7)) << 4));
          f32x4 s0 = {0.f, 0.f, 0.f, 0.f}, s1 = {0.f, 0.f, 0.f, 0.f};
#pragma unroll
          for (int ki = 0; ki < 4; ki++) {
            s0 = __builtin_amdgcn_mfma_f32_16x16x32_bf16(kf[ki], aq[0][ki], s0, 0, 0, 0);
            s1 = __builtin_amdgcn_mfma_f32_16x16x32_bf16(kf[ki], aq[1][ki], s1, 0, 0, 0);
          }
          s[0][nt] = s0; s[1][nt] = s1;
        }

        // hoist V^T tr-reads for kv-block b=0 (independent of softmax)
        short4v vl0[8], vh0[8];
#pragma unroll
        for (int on = 0; on < 8; on++) {
          unsigned a = trbase + (unsigned)(((on * 2) ^ swH) << 4);
          vl0[on] = ds_tr16<0>(a);
          vh0[on] = ds_tr16<1024>(a);
        }

        // ---- scale + causal mask: kv = kv0+nt*16+lhi*4+j, q = qr0+mf*16+llo ----
        const bool needm = (kv0 + KVBLK - 1 > qr0);
#pragma unroll
        for (int mf = 0; mf < 2; mf++) {
          const int qi = qr0 + mf * 16 + llo;
#pragma unroll
          for (int nt = 0; nt < 4; nt++) {
            const int kvb = kv0 + nt * 16 + lhi * 4;
#pragma unroll
            for (int j = 0; j < 4; j++) {
              float sv = s[mf][nt][j] * scale;
              if (needm && kvb + j > qi) sv = -1e30f;
              s[mf][nt][j] = sv;
            }
          }
        }

        // ---- softmax: in-register row reduce + 2 shfl; defer-max ----
#pragma unroll
        for (int mf = 0; mf < 2; mf++) {
          f32x4 mm = s[mf][0];
#pragma unroll
          for (int j = 0; j < 4; j++)
            mm[j] = fmaxf(fmaxf(s[mf][0][j], s[mf][1][j]), fmaxf(s[mf][2][j], s[mf][3][j]));
          float pmax = fmaxf(fmaxf(mm[0], mm[1]), fmaxf(mm[2], mm[3]));
          pmax = fmaxf(pmax, __shfl_xor(pmax, 16));
          pmax = fmaxf(pmax, __shfl_xor(pmax, 32));
          if (__any(pmax > mrow[mf] + 8.f)) {
            float mn = fmaxf(mrow[mf], pmax);
            float sc = __expf(mrow[mf] - mn);
            mrow[mf] = mn;
            lrow[mf] *= sc;
#pragma unroll
            for (int on = 0; on < 8; on++)
#pragma unroll
              for (int j = 0; j < 4; j++) acc[mf][on][j] *= sc;
          }
          float rs = 0.f;
#pragma unroll
          for (int nt = 0; nt < 4; nt++) {
            float p0 = __expf(s[mf][nt][0] - mrow[mf]);
            float p1 = __expf(s[mf][nt][1] - mrow[mf]);
            float p2 = __expf(s[mf][nt][2] - mrow[mf]);
            float p3 = __expf(s[mf][nt][3] - mrow[mf]);
            rs += (p0 + p1) + (p2 + p3);
            uint2 pk;
            pk.x = cvtpk_bf16(p0, p1);
            pk.y = cvtpk_bf16(p2, p3);
            *(uint2*)(pwB + (mf * 16 + llo) * 144 + nt * 32 + lhi * 8) = pk;
          }
          rs += __shfl_xor(rs, 16);
          rs += __shfl_xor(rs, 32);
          lrow[mf] += rs;
        }

        // ---- O^T += V^T P^T ----
        {
          short8 pf0 = *(const short8*)(pwB + llo * 144 + lhi * 16);
          short8 pf1 = *(const short8*)(pwB + (16 + llo) * 144 + lhi * 16);
          asm volatile("s_waitcnt lgkmcnt(0)" ::: "memory");
          __builtin_amdgcn_sched_barrier(0);
#pragma unroll
          for (int on = 0; on < 8; on++) {
            short8 vf = __builtin_shufflevector(vl0[on], vh0[on], 0, 1, 2, 3, 4, 5, 6, 7);
            acc[0][on] = __builtin_amdgcn_mfma_f32_16x16x32_bf16(vf, pf0, acc[0][on], 0, 0, 0);
            acc[1][on] = __builtin_amdgcn_mfma_f32_16x16x32_bf16(vf, pf1, acc[1][on], 0, 0, 0);
          }
        }
        {
          short8 pf0 = *(const short8*)(pwB + llo * 144 + 64 + lhi * 16);
          short8 pf1 = *(const short8*)(pwB + (16 + llo) * 144 + 64 + lhi * 16);
          short4v vl[8], vh[8];
#pragma unroll
          for (int on = 0; on < 8; on++) {
            unsigned a = trbase + (unsigned)(((on * 2) ^ swH) << 4);
            vl[on] = ds_tr16<8192>(a);
            vh[on] = ds_tr16<9216>(a);
          }
          asm volatile("s_waitcnt lgkmcnt(0)" ::: "memory");
          __builtin_amdgcn_sched_barrier(0);
#pragma unroll
          for (int on = 0; on < 8; on++) {
            short8 vf = __builtin_shufflevector(vl[on], vh[on], 0, 1, 2, 3, 4, 5, 6, 7);
            acc[0][on] = __builtin_amdgcn_mfma_f32_16x16x32_bf16(vf, pf0, acc[0][on], 0, 0, 0);
            acc[1][on] = __builtin_amdgcn_mfma_f32_16x16x32_bf16(vf, pf1, acc[1][on], 0, 0, 0);
          }
        }
      }  // active

      __syncthreads();
      if (t + 1 < ntile) {
#pragma unroll
        for (int r = 0; r < 4; r++) {
          *(short8*)((char*)Ks + (((r * 16 + srow) * 16 + schK0) << 4)) = kreg[r];
          *(short8*)((char*)Vs + (((r * 16 + srow) * 16 + schV0) << 4)) = vreg[r];
        }
      }
      __syncthreads();
    }

    // ---- epilogue: acc is O^T -> lane holds 4 consecutive d per (mf,on) ----
#pragma unroll
    for (int mf = 0; mf < 2; mf++) {
      const float ri = 1.0f / lrow[mf];
      ushort* orow = O + (size_t)(qr0 + mf * 16 + llo) * CDIM + h * HS + lhi * 4;
#pragma unroll
      for (int on = 0; on < 8; on++) {
        ushort4 o4;
        o4.x = f2bf(acc[mf][on][0] * ri);
        o4.y = f2bf(acc[mf][on][1] * ri);
        o4.z = f2bf(acc[mf][on][2] * ri);
        o4.w = f2bf(acc[mf][on][3] * ri);
        *(ushort4*)(orow + on * 16) = o4;
      }
    }
  }  // phase
}

// ---------------- launch ----------------
extern "C" void kernel_launch(void* const* d_in, const int* in_sizes, int n_in,
                              void* d_out, int out_size, void* d_ws, size_t ws_size,
                              hipStream_t stream) {
  const float* hs = (const float*)d_in[0];
  const int* pos = (const int*)d_in[1];
  const float* Wq = (const float*)d_in[2];
  const float* Wk = (const float*)d_in[3];
  const float* Wv = (const float*)d_in[4];
  const float* Wo = (const float*)d_in[5];
  float* out = (float*)d_out;

  const int T = 4096;
  const size_t elems = (size_t)T * CDIM;

  ushort* hsb  = (ushort*)d_ws;      // also reused as attention output
  ushort* wbuf = hsb + elems;        // current weight (bf16), reused 4x
  ushort* qb   = wbuf + elems;
  ushort* kb   = qb + elems;
  ushort* vb   = kb + elems;
  ushort* attn = hsb;

  const int n4 = (int)(elems / 4);
  const int castBlocks = (n4 + 255) / 256;

  cast_bf16_kernel<<<castBlocks, 256, 0, stream>>>(hs, hsb, n4);

  cast_bf16_kernel<<<castBlocks, 256, 0, stream>>>(Wq, wbuf, n4);
  gemm256<ushort><<<256, 512, 0, stream>>>(hsb, wbuf, qb);

  cast_bf16_kernel<<<castBlocks, 256, 0, stream>>>(Wk, wbuf, n4);
  gemm256<ushort><<<256, 512, 0, stream>>>(hsb, wbuf, kb);

  cast_bf16_kernel<<<castBlocks, 256, 0, stream>>>(Wv, wbuf, n4);
  gemm256<ushort><<<256, 512, 0, stream>>>(hsb, wbuf, vb);

  rope_kernel<<<(T * NH * 64) / 256, 256, 0, stream>>>(qb, kb, pos, T * NH);

  flash_attn<<<dim3(NQT / 2, NH), 256, 0, stream>>>(qb, kb, vb, attn);

  cast_bf16_kernel<<<castBlocks, 256, 0, stream>>>(Wo, wbuf, n4);
  gemm256<float><<<256, 512, 0, stream>>>(attn, wbuf, out);
}

// Round 7
// 830.024 us; speedup vs baseline: 2.7399x; 1.1665x over previous
//
#include <hip/hip_runtime.h>

typedef __attribute__((ext_vector_type(8))) short short8;
typedef __attribute__((ext_vector_type(4))) short short4v;
typedef __attribute__((ext_vector_type(4))) float f32x4;

#define NH 32
#define HS 128
#define CDIM 4096
#define QBLK 256
#define KVBLK 64
#define NQT 16  // T / QBLK

__device__ __forceinline__ ushort f2bf(float f) {
  union { float f; unsigned u; } a; a.f = f;
  unsigned u = a.u;
  return (ushort)((u + 0x7FFFu + ((u >> 16) & 1u)) >> 16);
}
__device__ __forceinline__ float bf2f(ushort h) {
  union { unsigned u; float f; } a; a.u = ((unsigned)h) << 16;
  return a.f;
}
__device__ __forceinline__ unsigned cvtpk_bf16(float lo, float hi) {
  unsigned r;
  asm("v_cvt_pk_bf16_f32 %0, %1, %2" : "=v"(r) : "v"(lo), "v"(hi));
  return r;
}

__device__ __forceinline__ void gld16(const void* g, void* l) {
  __builtin_amdgcn_global_load_lds((const __attribute__((address_space(1))) void*)g,
                                   (__attribute__((address_space(3))) void*)l, 16, 0, 0);
}

__device__ __forceinline__ unsigned lds_off(const void* p) {
  return (unsigned)(uintptr_t)(const __attribute__((address_space(3))) void*)p;
}

template<int OFF>
__device__ __forceinline__ short4v ds_tr16(unsigned addr) {
  short4v r;
  asm volatile("ds_read_b64_tr_b16 %0, %1 offset:%c2" : "=v"(r) : "v"(addr), "i"(OFF));
  return r;
}

// ---------------- fp32 -> bf16 cast (vectorized) ----------------
__global__ __launch_bounds__(256) void cast_bf16_kernel(const float* __restrict__ in,
                                                        ushort* __restrict__ out, int n4) {
  int i = blockIdx.x * 256 + threadIdx.x;
  if (i >= n4) return;
  float4 v = ((const float4*)in)[i];
  ushort4 o;
  o.x = f2bf(v.x); o.y = f2bf(v.y); o.z = f2bf(v.z); o.w = f2bf(v.w);
  ((ushort4*)out)[i] = o;
}

// ---------------- GEMM 256x256 8-phase (unchanged, verified round 5) ----------------
#define A00 0
#define A01 16384
#define A10 32768
#define A11 49152
#define B00 65536
#define B01 81920
#define B10 98304
#define B11 114688

template<typename OutT>
__global__ __launch_bounds__(512, 2) void gemm256(const ushort* __restrict__ A,
                                                  const ushort* __restrict__ B,
                                                  OutT* __restrict__ C) {
  __shared__ char sm[131072];
  const int tid = threadIdx.x;
  const int w = tid >> 6, lane = tid & 63, lhi = lane >> 4, llo = lane & 15;

  const int bid = blockIdx.x;
  const int x = (bid & 7) * 32 + (bid >> 3);
  const int mt = x >> 4, nt = x & 15;
  const size_t m0 = (size_t)mt * 256, n0 = (size_t)nt * 256;

  const char* A0p = (const char*)(A + m0 * 4096);
  const char* A1p = A0p + 1048576;
  const char* B0p = (const char*)(B + n0 * 4096);
  const char* B1p = B0p + 1048576;

  const int i0 = tid, i1 = tid + 512;
  const int ri0 = i0 >> 3, ri1 = i1 >> 3;
  const int cg0 = (i0 & 7) ^ (((ri0 >> 2) & 1) << 1);
  const int cg1 = (i1 & 7) ^ (((ri1 >> 2) & 1) << 1);
  const int off0 = ri0 * 8192 + cg0 * 16;
  const int off1 = ri1 * 8192 + cg1 * 16;
  const unsigned sd0 = (unsigned)(w * 1024);
  const unsigned sd1 = (unsigned)(8192 + w * 1024);

  const int sw = ((llo >> 2) & 1) << 1;
  const unsigned rd0 = (unsigned)((llo * 8 + ((0 * 4 + lhi) ^ sw)) * 16);
  const unsigned rd1 = (unsigned)((llo * 8 + ((1 * 4 + lhi) ^ sw)) * 16);

  const int wmg = w >> 2, wng = w & 3;
  const unsigned aE = wmg ? A01 : A00;
  const unsigned aO = wmg ? A11 : A10;
  const unsigned bE = (wng >> 1) ? B01 : B00;
  const unsigned bO = (wng >> 1) ? B11 : B10;
  const unsigned bco = (unsigned)((wng & 1) * 8192);

  f32x4 acc[8][4] = {};
  short8 a0[4], a1[4], u0[2], u1[2], v0[2], v1[2];

#define STG(PAN, K0, LB) do { \
    gld16((PAN) + (size_t)(K0) * 2 + off0, sm + (LB) + sd0); \
    gld16((PAN) + (size_t)(K0) * 2 + off1, sm + (LB) + sd1); \
  } while (0)
#define LDA(BASE, MQ) do { _Pragma("unroll") for (int m_ = 0; m_ < 4; m_++) { \
    a0[m_] = *(const short8*)(sm + (BASE) + (MQ) * 8192 + m_ * 2048 + rd0); \
    a1[m_] = *(const short8*)(sm + (BASE) + (MQ) * 8192 + m_ * 2048 + rd1); } } while (0)
#define LDB(R0, R1, BASE, NQ) do { _Pragma("unroll") for (int n_ = 0; n_ < 2; n_++) { \
    R0[n_] = *(const short8*)(sm + (BASE) + bco + (NQ) * 4096 + n_ * 2048 + rd0); \
    R1[n_] = *(const short8*)(sm + (BASE) + bco + (NQ) * 4096 + n_ * 2048 + rd1); } } while (0)
#define MM(MQ, NQ, R0, R1) do { \
    _Pragma("unroll") for (int m_ = 0; m_ < 4; m_++) _Pragma("unroll") for (int n_ = 0; n_ < 2; n_++) \
      acc[(MQ) * 4 + m_][(NQ) * 2 + n_] = __builtin_amdgcn_mfma_f32_16x16x32_bf16(a0[m_], R0[n_], acc[(MQ) * 4 + m_][(NQ) * 2 + n_], 0, 0, 0); \
    _Pragma("unroll") for (int m_ = 0; m_ < 4; m_++) _Pragma("unroll") for (int n_ = 0; n_ < 2; n_++) \
      acc[(MQ) * 4 + m_][(NQ) * 2 + n_] = __builtin_amdgcn_mfma_f32_16x16x32_bf16(a1[m_], R1[n_], acc[(MQ) * 4 + m_][(NQ) * 2 + n_], 0, 0, 0); \
  } while (0)
#define BAR1 do { __builtin_amdgcn_s_barrier(); \
    asm volatile("s_waitcnt lgkmcnt(0)" ::: "memory"); \
    __builtin_amdgcn_sched_barrier(0); \
    __builtin_amdgcn_s_setprio(1); } while (0)
#define BAR2 do { __builtin_amdgcn_s_setprio(0); __builtin_amdgcn_s_barrier(); \
    __builtin_amdgcn_sched_barrier(0); } while (0)

  STG(B0p, 0, B00); STG(B1p, 0, B01); STG(A0p, 0, A00); STG(A1p, 0, A01);
  STG(B0p, 64, B10); STG(B1p, 64, B11); STG(A0p, 64, A10); STG(A1p, 64, A11);
  asm volatile("s_waitcnt vmcnt(8)" ::: "memory");
  __builtin_amdgcn_s_barrier();
  __builtin_amdgcn_sched_barrier(0);

  for (int it = 0; it < 32; ++it) {
    const int kc = it * 128;
    const bool st = (it < 31);
    LDA(aE, 0); LDB(u0, u1, bE, 0);
    BAR1; MM(0, 0, u0, u1); BAR2;
    LDB(v0, v1, bE, 1);
    BAR1; MM(0, 1, v0, v1); BAR2;
    LDA(aE, 1);
    if (st) STG(B0p, kc + 128, B00);
    BAR1; MM(1, 1, v0, v1); BAR2;
    if (st) { STG(B1p, kc + 128, B01); STG(A0p, kc + 128, A00); }
    BAR1; MM(1, 0, u0, u1);
    __builtin_amdgcn_s_setprio(0);
    if (st) asm volatile("s_waitcnt vmcnt(6)" ::: "memory");
    else    asm volatile("s_waitcnt vmcnt(0)" ::: "memory");
    __builtin_amdgcn_s_barrier();
    __builtin_amdgcn_sched_barrier(0);
    LDA(aO, 0); LDB(u0, u1, bO, 0);
    if (st) STG(A1p, kc + 128, A01);
    BAR1; MM(0, 0, u0, u1); BAR2;
    LDB(v0, v1, bO, 1);
    BAR1; MM(0, 1, v0, v1); BAR2;
    LDA(aO, 1);
    if (st) { STG(B0p, kc + 192, B10); STG(B1p, kc + 192, B11); }
    BAR1; MM(1, 1, v0, v1); BAR2;
    if (st) { STG(A0p, kc + 192, A10); STG(A1p, kc + 192, A11); }
    BAR1; MM(1, 0, u0, u1);
    __builtin_amdgcn_s_setprio(0);
    if (st) asm volatile("s_waitcnt vmcnt(8)" ::: "memory");
    __builtin_amdgcn_s_barrier();
    __builtin_amdgcn_sched_barrier(0);
  }

  const int wm = wmg * 128, wn = wng * 64;
#pragma unroll
  for (int m = 0; m < 8; m++) {
#pragma unroll
    for (int nf = 0; nf < 4; nf++) {
      const size_t col = n0 + wn + nf * 16 + llo;
#pragma unroll
      for (int j = 0; j < 4; j++) {
        const size_t row = m0 + wm + m * 16 + lhi * 4 + j;
        if constexpr (sizeof(OutT) == 4)
          C[row * 4096 + col] = acc[m][nf][j];
        else
          C[row * 4096 + col] = f2bf(acc[m][nf][j]);
      }
    }
  }
#undef STG
#undef LDA
#undef LDB
#undef MM
#undef BAR1
#undef BAR2
}

// ---------------- RoPE (in-place on Q and K, bf16) ----------------
__global__ __launch_bounds__(256) void rope_kernel(ushort* __restrict__ Q,
                                                   ushort* __restrict__ Kb,
                                                   const int* __restrict__ pos_ids,
                                                   int nrows) {
  int gid = blockIdx.x * 256 + threadIdx.x;
  int d = gid & 63;
  int row = gid >> 6;
  if (row >= nrows) return;
  int t = row >> 5;
  int pos = pos_ids[t];
  float inv = expf((float)d * -0.14391156831212788f);  // -ln(10000)/64
  float ang = (float)pos * inv;
  float s, c;
  sincosf(ang, &s, &c);
  size_t base = (size_t)row * HS;
  {
    float x1 = bf2f(Q[base + d]), x2 = bf2f(Q[base + d + 64]);
    Q[base + d]      = f2bf(x1 * c - x2 * s);
    Q[base + d + 64] = f2bf(x2 * c + x1 * s);
  }
  {
    float x1 = bf2f(Kb[base + d]), x2 = bf2f(Kb[base + d + 64]);
    Kb[base + d]      = f2bf(x1 * c - x2 * s);
    Kb[base + d + 64] = f2bf(x2 * c + x1 * s);
  }
}

// ---------------- Causal flash attention (v5: 8 waves, QBLK=256) ----------------
// grid (NQT/2=8, NH); block (qb,h) processes q-tiles {qb, 15-qb} -> uniform 68 KV-iters.
// 8 waves x 32 q-rows. KVBLK=64 staged once per block (amortized over 8 waves).
// Wave-level math identical to v4: swapped QK^T, in-register softmax, defer-max,
// P^T via cvt_pk -> LDS -> b128 B-frags, PV via tr-read V^T. setprio around MFMA.
__global__ __launch_bounds__(512) void flash_attn(const ushort* __restrict__ Q,
                                                  const ushort* __restrict__ K,
                                                  const ushort* __restrict__ V,
                                                  ushort* __restrict__ O) {
  __shared__ __align__(16) ushort Ks[KVBLK * HS];
  __shared__ __align__(16) ushort Vs[KVBLK * HS];
  __shared__ __align__(16) ushort Ps[8][32 * 72];   // per-wave P^T tile: 32 rows x 144 B
  const int tid = threadIdx.x;
  const int w = tid >> 6, l = tid & 63, lhi = l >> 4, llo = l & 15;
  const int qbp = blockIdx.x, h = blockIdx.y;

  // tr-read per-lane constants (V path)
  const int g = llo >> 2, c = llo & 3;
  const int swz = g | ((lhi & 1) << 2);
  const int c1 = c >> 1;
  const int swL = swz & 1, swH = swz & 6;
  const unsigned trbase = lds_off(Vs) + (unsigned)((lhi * 8 + g) * 256 + ((c1 ^ swL) << 4) + (c & 1) * 8);

  // staging per-lane constants: 512 threads cover rows {srow, srow+32} x chunk sch
  const int srow = tid >> 4, sch = tid & 15;
  const int schK = sch ^ (srow & 7);                                  // (srow+32)&7 == srow&7
  const int schV = sch ^ ((srow & 3) | (((srow >> 3) & 1) << 2));     // same for +32

  char* pwB = (char*)Ps[w];
  const float scale = 0.08838834764831845f;  // 1/sqrt(128)

  short8 kreg[2], vreg[2];

  for (int ph = 0; ph < 2; ph++) {
    const int qt = ph ? (NQT - 1 - qbp) : qbp;
    const int qr0 = qt * QBLK + w * 32;
    const int ntile = 4 * qt + 4;

    short8 aq[2][4];
#pragma unroll
    for (int mf = 0; mf < 2; mf++) {
      const ushort* qp = Q + (size_t)(qr0 + mf * 16 + llo) * CDIM + h * HS + lhi * 8;
#pragma unroll
      for (int ki = 0; ki < 4; ki++) aq[mf][ki] = *(const short8*)(qp + ki * 32);
    }

    f32x4 acc[2][8] = {};
    float mrow[2] = {-1e30f, -1e30f};
    float lrow[2] = {0.f, 0.f};

    // prologue: stage tile 0
#pragma unroll
    for (int r = 0; r < 2; r++) {
      const size_t rb = (size_t)(srow + r * 32) * CDIM + h * HS + sch * 8;
      kreg[r] = *(const short8*)(K + rb);
      vreg[r] = *(const short8*)(V + rb);
    }
#pragma unroll
    for (int r = 0; r < 2; r++) {
      const int row = srow + r * 32;
      *(short8*)((char*)Ks + ((row * 16 + schK) << 4)) = kreg[r];
      *(short8*)((char*)Vs + ((row * 16 + schV) << 4)) = vreg[r];
    }
    __syncthreads();

    for (int t = 0; t < ntile; t++) {
      const int kv0 = t * KVBLK;
      if (t + 1 < ntile) {
        const size_t rb = (size_t)(kv0 + KVBLK + srow) * CDIM + h * HS + sch * 8;
#pragma unroll
        for (int r = 0; r < 2; r++) {
          kreg[r] = *(const short8*)(K + rb + (size_t)r * 32 * CDIM);
          vreg[r] = *(const short8*)(V + rb + (size_t)r * 32 * CDIM);
        }
      }
      const bool active = (kv0 <= qr0 + 31);
      if (active) {
        // ---- S^T = K Q^T ----
        f32x4 s[2][4];
        __builtin_amdgcn_s_setprio(1);
#pragma unroll
        for (int nt = 0; nt < 4; nt++) {
          const int krow = nt * 16 + llo;
          const char* kr = (const char*)Ks + krow * 256;
          short8 kf[4];
#pragma unroll
          for (int ki = 0; ki < 4; ki++)
            kf[ki] = *(const short8*)(kr + (((ki * 4 + lhi) ^ (krow & 7)) << 4));
          f32x4 s0 = {0.f, 0.f, 0.f, 0.f}, s1 = {0.f, 0.f, 0.f, 0.f};
#pragma unroll
          for (int ki = 0; ki < 4; ki++) {
            s0 = __builtin_amdgcn_mfma_f32_16x16x32_bf16(kf[ki], aq[0][ki], s0, 0, 0, 0);
            s1 = __builtin_amdgcn_mfma_f32_16x16x32_bf16(kf[ki], aq[1][ki], s1, 0, 0, 0);
          }
          s[0][nt] = s0; s[1][nt] = s1;
        }
        __builtin_amdgcn_s_setprio(0);

        // hoist V^T tr-reads for kv-block b=0
        short4v vl0[8], vh0[8];
#pragma unroll
        for (int on = 0; on < 8; on++) {
          unsigned a = trbase + (unsigned)(((on * 2) ^ swH) << 4);
          vl0[on] = ds_tr16<0>(a);
          vh0[on] = ds_tr16<1024>(a);
        }

        // ---- scale + causal mask ----
        const bool needm = (kv0 + KVBLK - 1 > qr0);
#pragma unroll
        for (int mf = 0; mf < 2; mf++) {
          const int qi = qr0 + mf * 16 + llo;
#pragma unroll
          for (int nt = 0; nt < 4; nt++) {
            const int kvb = kv0 + nt * 16 + lhi * 4;
#pragma unroll
            for (int j = 0; j < 4; j++) {
              float sv = s[mf][nt][j] * scale;
              if (needm && kvb + j > qi) sv = -1e30f;
              s[mf][nt][j] = sv;
            }
          }
        }

        // ---- softmax: in-register row reduce + 2 shfl; defer-max ----
#pragma unroll
        for (int mf = 0; mf < 2; mf++) {
          f32x4 mm;
#pragma unroll
          for (int j = 0; j < 4; j++)
            mm[j] = fmaxf(fmaxf(s[mf][0][j], s[mf][1][j]), fmaxf(s[mf][2][j], s[mf][3][j]));
          float pmax = fmaxf(fmaxf(mm[0], mm[1]), fmaxf(mm[2], mm[3]));
          pmax = fmaxf(pmax, __shfl_xor(pmax, 16));
          pmax = fmaxf(pmax, __shfl_xor(pmax, 32));
          if (__any(pmax > mrow[mf] + 8.f)) {
            float mn = fmaxf(mrow[mf], pmax);
            float sc = __expf(mrow[mf] - mn);
            mrow[mf] = mn;
            lrow[mf] *= sc;
#pragma unroll
            for (int on = 0; on < 8; on++)
#pragma unroll
              for (int j = 0; j < 4; j++) acc[mf][on][j] *= sc;
          }
          float rs = 0.f;
#pragma unroll
          for (int nt = 0; nt < 4; nt++) {
            float p0 = __expf(s[mf][nt][0] - mrow[mf]);
            float p1 = __expf(s[mf][nt][1] - mrow[mf]);
            float p2 = __expf(s[mf][nt][2] - mrow[mf]);
            float p3 = __expf(s[mf][nt][3] - mrow[mf]);
            rs += (p0 + p1) + (p2 + p3);
            uint2 pk;
            pk.x = cvtpk_bf16(p0, p1);
            pk.y = cvtpk_bf16(p2, p3);
            *(uint2*)(pwB + (mf * 16 + llo) * 144 + nt * 32 + lhi * 8) = pk;
          }
          rs += __shfl_xor(rs, 16);
          rs += __shfl_xor(rs, 32);
          lrow[mf] += rs;
        }

        // ---- O^T += V^T P^T ----
        {
          short8 pf0 = *(const short8*)(pwB + llo * 144 + lhi * 16);
          short8 pf1 = *(const short8*)(pwB + (16 + llo) * 144 + lhi * 16);
          asm volatile("s_waitcnt lgkmcnt(0)" ::: "memory");
          __builtin_amdgcn_sched_barrier(0);
          __builtin_amdgcn_s_setprio(1);
#pragma unroll
          for (int on = 0; on < 8; on++) {
            short8 vf = __builtin_shufflevector(vl0[on], vh0[on], 0, 1, 2, 3, 4, 5, 6, 7);
            acc[0][on] = __builtin_amdgcn_mfma_f32_16x16x32_bf16(vf, pf0, acc[0][on], 0, 0, 0);
            acc[1][on] = __builtin_amdgcn_mfma_f32_16x16x32_bf16(vf, pf1, acc[1][on], 0, 0, 0);
          }
          __builtin_amdgcn_s_setprio(0);
        }
        {
          short8 pf0 = *(const short8*)(pwB + llo * 144 + 64 + lhi * 16);
          short8 pf1 = *(const short8*)(pwB + (16 + llo) * 144 + 64 + lhi * 16);
          short4v vl[8], vh[8];
#pragma unroll
          for (int on = 0; on < 8; on++) {
            unsigned a = trbase + (unsigned)(((on * 2) ^ swH) << 4);
            vl[on] = ds_tr16<8192>(a);
            vh[on] = ds_tr16<9216>(a);
          }
          asm volatile("s_waitcnt lgkmcnt(0)" ::: "memory");
          __builtin_amdgcn_sched_barrier(0);
          __builtin_amdgcn_s_setprio(1);
#pragma unroll
          for (int on = 0; on < 8; on++) {
            short8 vf = __builtin_shufflevector(vl[on], vh[on], 0, 1, 2, 3, 4, 5, 6, 7);
            acc[0][on] = __builtin_amdgcn_mfma_f32_16x16x32_bf16(vf, pf0, acc[0][on], 0, 0, 0);
            acc[1][on] = __builtin_amdgcn_mfma_f32_16x16x32_bf16(vf, pf1, acc[1][on], 0, 0, 0);
          }
          __builtin_amdgcn_s_setprio(0);
        }
      }  // active

      __syncthreads();
      if (t + 1 < ntile) {
#pragma unroll
        for (int r = 0; r < 2; r++) {
          const int row = srow + r * 32;
          *(short8*)((char*)Ks + ((row * 16 + schK) << 4)) = kreg[r];
          *(short8*)((char*)Vs + ((row * 16 + schV) << 4)) = vreg[r];
        }
      }
      __syncthreads();
    }

    // ---- epilogue: acc is O^T -> lane holds 4 consecutive d per (mf,on) ----
#pragma unroll
    for (int mf = 0; mf < 2; mf++) {
      const float ri = 1.0f / lrow[mf];
      ushort* orow = O + (size_t)(qr0 + mf * 16 + llo) * CDIM + h * HS + lhi * 4;
#pragma unroll
      for (int on = 0; on < 8; on++) {
        ushort4 o4;
        o4.x = f2bf(acc[mf][on][0] * ri);
        o4.y = f2bf(acc[mf][on][1] * ri);
        o4.z = f2bf(acc[mf][on][2] * ri);
        o4.w = f2bf(acc[mf][on][3] * ri);
        *(ushort4*)(orow + on * 16) = o4;
      }
    }
  }  // phase
}

// ---------------- launch ----------------
extern "C" void kernel_launch(void* const* d_in, const int* in_sizes, int n_in,
                              void* d_out, int out_size, void* d_ws, size_t ws_size,
                              hipStream_t stream) {
  const float* hs = (const float*)d_in[0];
  const int* pos = (const int*)d_in[1];
  const float* Wq = (const float*)d_in[2];
  const float* Wk = (const float*)d_in[3];
  const float* Wv = (const float*)d_in[4];
  const float* Wo = (const float*)d_in[5];
  float* out = (float*)d_out;

  const int T = 4096;
  const size_t elems = (size_t)T * CDIM;

  ushort* hsb  = (ushort*)d_ws;      // also reused as attention output
  ushort* wbuf = hsb + elems;        // current weight (bf16), reused 4x
  ushort* qb   = wbuf + elems;
  ushort* kb   = qb + elems;
  ushort* vb   = kb + elems;
  ushort* attn = hsb;

  const int n4 = (int)(elems / 4);
  const int castBlocks = (n4 + 255) / 256;

  cast_bf16_kernel<<<castBlocks, 256, 0, stream>>>(hs, hsb, n4);

  cast_bf16_kernel<<<castBlocks, 256, 0, stream>>>(Wq, wbuf, n4);
  gemm256<ushort><<<256, 512, 0, stream>>>(hsb, wbuf, qb);

  cast_bf16_kernel<<<castBlocks, 256, 0, stream>>>(Wk, wbuf, n4);
  gemm256<ushort><<<256, 512, 0, stream>>>(hsb, wbuf, kb);

  cast_bf16_kernel<<<castBlocks, 256, 0, stream>>>(Wv, wbuf, n4);
  gemm256<ushort><<<256, 512, 0, stream>>>(hsb, wbuf, vb);

  rope_kernel<<<(T * NH * 64) / 256, 256, 0, stream>>>(qb, kb, pos, T * NH);

  flash_attn<<<dim3(NQT / 2, NH), 512, 0, stream>>>(qb, kb, vb, attn);

  cast_bf16_kernel<<<castBlocks, 256, 0, stream>>>(Wo, wbuf, n4);
  gemm256<float><<<256, 512, 0, stream>>>(attn, wbuf, out);
}